// Round 4
// baseline (180.189 us; speedup 1.0000x reference)
//
#include <hip/hip_runtime.h>
#include <hip/hip_bf16.h>
#include <math.h>

#define SA_N 2048
#define SA_D 1024
#define SA_H 16
#define SA_HD 64

typedef __attribute__((ext_vector_type(8))) short bf16x8;
typedef __attribute__((ext_vector_type(4))) float f32x4;
typedef __attribute__((address_space(3))) void lds_t;
typedef __attribute__((address_space(1))) void gmem_t;

#define SC2 0.18033688011112042f   // (1/sqrt(64)) * log2(e), folded into Wq/bq

// ---------------- merged prep: x->bf16 and 4x W[K][N] -> bf16 Wt[N][K] ----------------
__global__ __launch_bounds__(256) void prep_kernel(
    const float* __restrict__ x,
    const float* __restrict__ Wq, const float* __restrict__ Wk,
    const float* __restrict__ Wv, const float* __restrict__ Wo,
    __hip_bfloat16* __restrict__ xbf, __hip_bfloat16* __restrict__ WtAll)
{
    const int tid = threadIdx.x;
    const int z = blockIdx.z;
    if (z < 2) {
        const int r = z * 1024 + blockIdx.y * 32 + (tid >> 3);
        const int c = blockIdx.x * 32 + (tid & 7) * 4;
        const size_t idx = (size_t)r * SA_D + c;
        float4 v = *reinterpret_cast<const float4*>(&x[idx]);
        union { __hip_bfloat16 hh[4]; short4 s4; } u;
        u.hh[0] = __float2bfloat16(v.x);
        u.hh[1] = __float2bfloat16(v.y);
        u.hh[2] = __float2bfloat16(v.z);
        u.hh[3] = __float2bfloat16(v.w);
        *reinterpret_cast<short4*>(&xbf[idx]) = u.s4;
    } else {
        const int w = z - 2;
        const float* W = (w == 0) ? Wq : (w == 1) ? Wk : (w == 2) ? Wv : Wo;
        const float scale = (w == 0) ? SC2 : 1.0f;
        __hip_bfloat16* Wt = WtAll + (size_t)w * SA_D * SA_D;
        __shared__ float t[32][33];
        const int c0 = blockIdx.x * 32, r0 = blockIdx.y * 32;
        const int tx = tid & 31, ty = tid >> 5;
#pragma unroll
        for (int p = 0; p < 4; ++p)
            t[ty + p * 8][tx] = W[(size_t)(r0 + ty + p * 8) * SA_D + c0 + tx] * scale;
        __syncthreads();
#pragma unroll
        for (int p = 0; p < 4; ++p)
            Wt[(size_t)(c0 + ty + p * 8) * SA_D + r0 + tx] =
                __float2bfloat16(t[tx][ty + p * 8]);
    }
}

// ---------------- fused QKV GEMM, m97-class tile: BM=128 BN=64 BK=64 ----------------
__global__ __launch_bounds__(256) void gemm_qkv_kernel(
    const __hip_bfloat16* __restrict__ xbf, const __hip_bfloat16* __restrict__ WtAll,
    const float* __restrict__ bq, const float* __restrict__ bk, const float* __restrict__ bv,
    __hip_bfloat16* __restrict__ Qb, __hip_bfloat16* __restrict__ Kb,
    __hip_bfloat16* __restrict__ VtT)
{
    __shared__ __align__(16) char As[128 * 128];   // 128 rows x 64 bf16
    __shared__ __align__(16) char Bs[64 * 128];    // 64 cols  x 64 bf16

    const int tid = threadIdx.x;
    const int wave = tid >> 6, lane = tid & 63;
    const int m = lane & 15, quad = lane >> 4;
    const int wm = wave >> 1, wn = wave & 1;
    const int row0 = blockIdx.y * 128;
    const int col0 = blockIdx.x * 64;          // 0..3071 over concat(Q,K,V)
    const int w = col0 >> 10;                  // which weight (0=Q,1=K,2=V)
    const int cw0 = col0 & 1023;               // col within that weight
    const __hip_bfloat16* Bt = WtAll + (size_t)w * SA_D * SA_D;

    f32x4 acc[4][2];
#pragma unroll
    for (int mi = 0; mi < 4; ++mi)
#pragma unroll
        for (int ni = 0; ni < 2; ++ni) acc[mi][ni] = (f32x4){0.f, 0.f, 0.f, 0.f};

    const int sr = tid >> 3;   // 0..31
    const int sc = tid & 7;    // 16B chunk

    for (int k0 = 0; k0 < SA_D; k0 += 64) {
#pragma unroll
        for (int p = 0; p < 4; ++p) {
            const int r = p * 32 + sr;
            const int pc = (sc ^ (r & 7)) * 16;
            const char* ga = (const char*)(xbf + (size_t)(row0 + r) * SA_D + k0) + pc;
            __builtin_amdgcn_global_load_lds((gmem_t*)ga,
                (lds_t*)(As + p * 4096 + wave * 1024), 16, 0, 0);
        }
#pragma unroll
        for (int p = 0; p < 2; ++p) {
            const int r = p * 32 + sr;
            const int pc = (sc ^ (r & 7)) * 16;
            const char* gb = (const char*)(Bt + (size_t)(cw0 + r) * SA_D + k0) + pc;
            __builtin_amdgcn_global_load_lds((gmem_t*)gb,
                (lds_t*)(Bs + p * 4096 + wave * 1024), 16, 0, 0);
        }
        __syncthreads();

#pragma unroll
        for (int s = 0; s < 2; ++s) {
            bf16x8 af[4], bfr[2];
#pragma unroll
            for (int mi = 0; mi < 4; ++mi) {
                const int row = wm * 64 + mi * 16 + m;
                const int pc = (s * 4 + quad) ^ (row & 7);
                af[mi] = *reinterpret_cast<const bf16x8*>(As + row * 128 + pc * 16);
            }
#pragma unroll
            for (int ni = 0; ni < 2; ++ni) {
                const int col = wn * 32 + ni * 16 + m;
                const int pc = (s * 4 + quad) ^ (col & 7);
                bfr[ni] = *reinterpret_cast<const bf16x8*>(Bs + col * 128 + pc * 16);
            }
#pragma unroll
            for (int mi = 0; mi < 4; ++mi)
#pragma unroll
                for (int ni = 0; ni < 2; ++ni)
                    acc[mi][ni] = __builtin_amdgcn_mfma_f32_16x16x32_bf16(
                        af[mi], bfr[ni], acc[mi][ni], 0, 0, 0);
        }
        __syncthreads();
    }

    // epilogue: Q,K natural bf16; V transposed [dim][key] with per-64-block key
    // permutation jp = (j&15)*4 + (j>>4), j = mi*16 + quad*4 + reg.
    if (w < 2) {
        __hip_bfloat16* Out = w ? Kb : Qb;
        const float* bb = w ? bk : bq;
        const float bscale = w ? 1.0f : SC2;
#pragma unroll
        for (int ni = 0; ni < 2; ++ni) {
            const int cw = cw0 + wn * 32 + ni * 16 + m;
            const float bvv = bb[cw] * bscale;
#pragma unroll
            for (int mi = 0; mi < 4; ++mi) {
                const int rbase = row0 + wm * 64 + mi * 16 + quad * 4;
#pragma unroll
                for (int reg = 0; reg < 4; ++reg)
                    Out[(size_t)(rbase + reg) * SA_D + cw] =
                        __float2bfloat16(acc[mi][ni][reg] + bvv);
            }
        }
    } else {
#pragma unroll
        for (int ni = 0; ni < 2; ++ni) {
            const int cw = cw0 + wn * 32 + ni * 16 + m;
            const float bvv = bv[cw];
            const int kblk = row0 + wm * 64;   // 64-aligned key-block base
#pragma unroll
            for (int mi = 0; mi < 4; ++mi) {
#pragma unroll
                for (int reg = 0; reg < 4; ++reg) {
                    const int jp = (quad * 4 + reg) * 4 + mi;
                    VtT[(size_t)cw * SA_N + kblk + jp] =
                        __float2bfloat16(acc[mi][ni][reg] + bvv);
                }
            }
        }
    }
}

// ---------------- bf16 MFMA GEMM 64x64 (out-proj, exact R12) ----------------
__global__ __launch_bounds__(256) void gemm_out_kernel(
    const __hip_bfloat16* __restrict__ A, const __hip_bfloat16* __restrict__ Bt,
    const float* __restrict__ bias, float* __restrict__ Cout)
{
    __shared__ __align__(16) char As[64 * 128];
    __shared__ __align__(16) char Bs[64 * 128];
    const int tid = threadIdx.x;
    const int wave = tid >> 6, lane = tid & 63;
    const int m = lane & 15, quad = lane >> 4;
    const int wm = wave >> 1, wn = wave & 1;
    const int row0 = blockIdx.y * 64, col0 = blockIdx.x * 64;

    f32x4 acc[2][2];
#pragma unroll
    for (int i = 0; i < 2; ++i)
#pragma unroll
        for (int j = 0; j < 2; ++j) acc[i][j] = (f32x4){0.f, 0.f, 0.f, 0.f};

    const int sr = tid >> 3;
    const int sc = tid & 7;

    for (int k0 = 0; k0 < SA_D; k0 += 64) {
#pragma unroll
        for (int p = 0; p < 2; ++p) {
            const int r = p * 32 + sr;
            const int pc = (sc ^ (r & 7)) * 16;
            const char* ga = (const char*)(A + (size_t)(row0 + r) * SA_D + k0) + pc;
            __builtin_amdgcn_global_load_lds((gmem_t*)ga,
                (lds_t*)(As + p * 4096 + wave * 1024), 16, 0, 0);
            const char* gb = (const char*)(Bt + (size_t)(col0 + r) * SA_D + k0) + pc;
            __builtin_amdgcn_global_load_lds((gmem_t*)gb,
                (lds_t*)(Bs + p * 4096 + wave * 1024), 16, 0, 0);
        }
        __syncthreads();

#pragma unroll
        for (int s = 0; s < 2; ++s) {
            bf16x8 af[2], bfr[2];
#pragma unroll
            for (int mi = 0; mi < 2; ++mi) {
                const int row = wm * 32 + mi * 16 + m;
                const int pc = (s * 4 + quad) ^ (row & 7);
                af[mi] = *reinterpret_cast<const bf16x8*>(As + row * 128 + pc * 16);
            }
#pragma unroll
            for (int ni = 0; ni < 2; ++ni) {
                const int col = wn * 32 + ni * 16 + m;
                const int pc = (s * 4 + quad) ^ (col & 7);
                bfr[ni] = *reinterpret_cast<const bf16x8*>(Bs + col * 128 + pc * 16);
            }
#pragma unroll
            for (int mi = 0; mi < 2; ++mi)
#pragma unroll
                for (int ni = 0; ni < 2; ++ni)
                    acc[mi][ni] = __builtin_amdgcn_mfma_f32_16x16x32_bf16(
                        af[mi], bfr[ni], acc[mi][ni], 0, 0, 0);
        }
        __syncthreads();
    }

#pragma unroll
    for (int ni = 0; ni < 2; ++ni) {
        const int col = col0 + wn * 32 + ni * 16 + m;
        const float bv = bias[col];
#pragma unroll
        for (int mi = 0; mi < 2; ++mi) {
            const int rbase = row0 + wm * 32 + mi * 16 + quad * 4;
#pragma unroll
            for (int reg = 0; reg < 4; ++reg)
                Cout[(size_t)(rbase + reg) * SA_D + col] = acc[mi][ni][reg] + bv;
        }
    }
}

// ---------------- MFMA flash attention v10: barrier-free direct-global K/V ----------
// K+V per head = 512 KB, L2-resident (learn_hip m169 lesson: don't LDS-stage
// cache-fit data). MFMA fragments for K and V are read DIRECTLY from global:
// the old staged-swizzle pair (swizzled DMA source + swizzled ds_read) cancels,
// so the direct address is just the natural fragment location. The Ps round
// trip is intra-wave (each wave reads only the 16 rows it wrote), so with
// staging gone the main loop has NO barriers: 16 waves/CU run self-paced and
// TLP hides the L1/L2 gather latency. LDS drops 58.6->27 KB; the group merge
// reuses the dead Ps space.
__global__ __launch_bounds__(512, 4) void flash_mfma_kernel(
    const __hip_bfloat16* __restrict__ Qb,  // [N][D], pre-scaled by SC2
    const __hip_bfloat16* __restrict__ Kb,  // [N][D]
    const __hip_bfloat16* __restrict__ Vt,  // [D][N], keys permuted per 64-block
    __hip_bfloat16* __restrict__ O)         // [N][D]
{
    const int b = blockIdx.x;
    const int h = b & 15;
    const int qraw = b >> 4;
    const int qt = (qraw < 16) ? qraw : 47 - qraw;  // fold for CU balance
    const int row0 = qt * 64;
    const int ntiles = (qt >> 1) + 1;               // 128-key tiles

    const int tid = threadIdx.x;
    const int wave = tid >> 6, lane = tid & 63;
    const int g = wave >> 2, w4 = wave & 3;         // group, wave-in-group
    const int ln = lane & 15, quad = lane >> 4;

    __shared__ __align__(16) char Qs[64 * 128];     // [qrow][dim] bf16 (dead after hoist)
    __shared__ __align__(16) char Ps[2][64 * 144];  // per-group [qrow][key'] bf16; merge buf after loop
    __shared__ float lmerge[64];

    // stage Q tile once (DMA; drained by the barrier below)
    {
        const int r = wave * 8 + (lane >> 3);
        const int pc = ((lane & 7) ^ (r & 7)) * 16;
        const char* gq = (const char*)(Qb + (size_t)(row0 + r) * SA_D + h * SA_HD) + pc;
        __builtin_amdgcn_global_load_lds((gmem_t*)gq,
            (lds_t*)(Qs + wave * 1024), 16, 0, 0);
    }
    __syncthreads();

    // hoist loop-invariant Q fragments into registers
    bf16x8 afh[2];
    {
        const int mrow = w4 * 16 + ln;
#pragma unroll
        for (int s = 0; s < 2; ++s) {
            const int pca = (s * 4 + quad) ^ (mrow & 7);
            afh[s] = *reinterpret_cast<const bf16x8*>(Qs + mrow * 128 + pca * 16);
        }
    }

    f32x4 oacc[4], lacc;
#pragma unroll
    for (int dg = 0; dg < 4; ++dg) oacc[dg] = (f32x4){0.f, 0.f, 0.f, 0.f};
    lacc = (f32x4){0.f, 0.f, 0.f, 0.f};

    const short one_bf = (short)0x3F80;
    const bf16x8 ones = {one_bf, one_bf, one_bf, one_bf, one_bf, one_bf, one_bf, one_bf};

    // direct-fragment base addresses (bytes)
    //   K frag (s,gg): Kb + (kt*128 + g*64 + gg*16 + ln)*2048 + h*128 + (s*4+quad)*16
    //   V frag (s2,dg): Vt + (h*64 + dg*16 + ln)*4096 + kt*256 + (g*8+s2*4+quad)*16
    const char* Kb8 = (const char*)Kb + (size_t)(g * 64 + ln) * 2048 + h * 128 + quad * 16;
    const char* Vt8 = (const char*)Vt + (size_t)(h * 64 + ln) * 4096 + (g * 8 + quad) * 16;

    for (int kt = 0; kt < ntiles; ++kt) {
        // S = Q K^T : wave's 16 q-rows x group's 64 keys (K direct from global)
        f32x4 sacc[4];
#pragma unroll
        for (int gg = 0; gg < 4; ++gg) sacc[gg] = (f32x4){0.f, 0.f, 0.f, 0.f};
        const char* Kt = Kb8 + (size_t)kt * 128 * 2048;
        __builtin_amdgcn_s_setprio(1);
#pragma unroll
        for (int s = 0; s < 2; ++s) {
#pragma unroll
            for (int gg = 0; gg < 4; ++gg) {
                bf16x8 bf = *reinterpret_cast<const bf16x8*>(
                    Kt + (size_t)(gg * 16) * 2048 + s * 64);
                sacc[gg] = __builtin_amdgcn_mfma_f32_16x16x32_bf16(afh[s], bf, sacc[gg], 0, 0, 0);
            }
        }
        __builtin_amdgcn_s_setprio(0);

        // P = exp2(S) + causal mask; packed b64 store per row (permuted keys)
        const bool last = (kt == ntiles - 1);
        const int prow_b = w4 * 16 + quad * 4;
        const int qrow_b = row0 + prow_b;
        char* Pg = Ps[g];
#pragma unroll
        for (int reg = 0; reg < 4; ++reg) {
            union { __hip_bfloat16 hh[4]; short4 s4; } u;
#pragma unroll
            for (int gg = 0; gg < 4; ++gg) {
                const int key = kt * 128 + g * 64 + gg * 16 + ln;
                float p = exp2f(sacc[gg][reg]);
                if (last && key > (qrow_b + reg)) p = 0.f;
                u.hh[gg] = __float2bfloat16(p);
            }
            *reinterpret_cast<short4*>(Pg + (prow_b + reg) * 144 + ln * 8) = u.s4;
        }

        // O += P V ; l += P . ones   (V direct from global; k' order consistent)
        const char* Vtk = Vt8 + (size_t)kt * 256;
        __builtin_amdgcn_s_setprio(1);
#pragma unroll
        for (int s2 = 0; s2 < 2; ++s2) {
            bf16x8 pf = *reinterpret_cast<const bf16x8*>(
                Pg + (w4 * 16 + ln) * 144 + s2 * 64 + quad * 16);
            lacc = __builtin_amdgcn_mfma_f32_16x16x32_bf16(pf, ones, lacc, 0, 0, 0);
#pragma unroll
            for (int dg = 0; dg < 4; ++dg) {
                bf16x8 vf = *reinterpret_cast<const bf16x8*>(
                    Vtk + (size_t)(dg * 16) * 4096 + s2 * 64);
                oacc[dg] = __builtin_amdgcn_mfma_f32_16x16x32_bf16(pf, vf, oacc[dg], 0, 0, 0);
            }
        }
        __builtin_amdgcn_s_setprio(0);
    }

    // merge groups: group 1 dumps fp32 partials into Ps space (16 KB = 64x64 f32)
    __syncthreads();
    float* Mf = reinterpret_cast<float*>(Ps);
    if (g == 1) {
#pragma unroll
        for (int reg = 0; reg < 4; ++reg) {
            const int row = w4 * 16 + quad * 4 + reg;
#pragma unroll
            for (int dg = 0; dg < 4; ++dg)
                Mf[row * 64 + dg * 16 + ln] = oacc[dg][reg];
            if (ln == 0) lmerge[row] = lacc[reg];
        }
    }
    __syncthreads();
    if (g == 0) {
#pragma unroll
        for (int reg = 0; reg < 4; ++reg) {
            const int row = w4 * 16 + quad * 4 + reg;
            const float inv = 1.0f / (lacc[reg] + lmerge[row]);
            const int qrow = row0 + row;
#pragma unroll
            for (int dg = 0; dg < 4; ++dg)
                O[(size_t)qrow * SA_D + h * SA_HD + dg * 16 + ln] =
                    __float2bfloat16((oacc[dg][reg] + Mf[row * 64 + dg * 16 + ln]) * inv);
        }
    }
}

extern "C" void kernel_launch(void* const* d_in, const int* in_sizes, int n_in,
                              void* d_out, int out_size, void* d_ws, size_t ws_size,
                              hipStream_t stream) {
    const float* x  = (const float*)d_in[0];
    const float* Wq = (const float*)d_in[1];
    const float* bq = (const float*)d_in[2];
    const float* Wk = (const float*)d_in[3];
    const float* bk = (const float*)d_in[4];
    const float* Wv = (const float*)d_in[5];
    const float* bv = (const float*)d_in[6];
    const float* Wo = (const float*)d_in[7];
    const float* bo = (const float*)d_in[8];
    float* out = (float*)d_out;

    const size_t ND = (size_t)SA_N * SA_D;
    const size_t DD = (size_t)SA_D * SA_D;
    __hip_bfloat16* xbf   = (__hip_bfloat16*)d_ws;
    __hip_bfloat16* WtAll = xbf + ND;
    __hip_bfloat16* Qb    = WtAll + 4 * DD;
    __hip_bfloat16* Kb    = Qb + ND;
    __hip_bfloat16* VtT   = Kb + ND;
    __hip_bfloat16* Abf   = VtT + ND;

    prep_kernel<<<dim3(32, 32, 6), 256, 0, stream>>>(x, Wq, Wk, Wv, Wo, xbf, WtAll);
    gemm_qkv_kernel<<<dim3(3072 / 64, SA_N / 128), 256, 0, stream>>>(
        xbf, WtAll, bq, bk, bv, Qb, Kb, VtT);
    flash_mfma_kernel<<<dim3(512), 512, 0, stream>>>(Qb, Kb, VtT, Abf);
    gemm_out_kernel<<<dim3(SA_D / 64, SA_N / 64), 256, 0, stream>>>(
        Abf, WtAll + 3 * DD, bo, out);
}

// Round 5
// 157.375 us; speedup vs baseline: 1.1450x; 1.1450x over previous
//
#include <hip/hip_runtime.h>
#include <hip/hip_bf16.h>
#include <math.h>

#define SA_N 2048
#define SA_D 1024
#define SA_H 16
#define SA_HD 64

typedef __attribute__((ext_vector_type(8))) short bf16x8;
typedef __attribute__((ext_vector_type(4))) float f32x4;
typedef __attribute__((address_space(3))) void lds_t;
typedef __attribute__((address_space(1))) void gmem_t;

#define SC2 0.18033688011112042f   // (1/sqrt(64)) * log2(e), folded into Wq/bq

// ---------------- merged prep: x->bf16 and 4x W[K][N] -> bf16 Wt[N][K] ----------------
__global__ __launch_bounds__(256) void prep_kernel(
    const float* __restrict__ x,
    const float* __restrict__ Wq, const float* __restrict__ Wk,
    const float* __restrict__ Wv, const float* __restrict__ Wo,
    __hip_bfloat16* __restrict__ xbf, __hip_bfloat16* __restrict__ WtAll)
{
    const int tid = threadIdx.x;
    const int z = blockIdx.z;
    if (z < 2) {
        const int r = z * 1024 + blockIdx.y * 32 + (tid >> 3);
        const int c = blockIdx.x * 32 + (tid & 7) * 4;
        const size_t idx = (size_t)r * SA_D + c;
        float4 v = *reinterpret_cast<const float4*>(&x[idx]);
        union { __hip_bfloat16 hh[4]; short4 s4; } u;
        u.hh[0] = __float2bfloat16(v.x);
        u.hh[1] = __float2bfloat16(v.y);
        u.hh[2] = __float2bfloat16(v.z);
        u.hh[3] = __float2bfloat16(v.w);
        *reinterpret_cast<short4*>(&xbf[idx]) = u.s4;
    } else {
        const int w = z - 2;
        const float* W = (w == 0) ? Wq : (w == 1) ? Wk : (w == 2) ? Wv : Wo;
        const float scale = (w == 0) ? SC2 : 1.0f;
        __hip_bfloat16* Wt = WtAll + (size_t)w * SA_D * SA_D;
        __shared__ float t[32][33];
        const int c0 = blockIdx.x * 32, r0 = blockIdx.y * 32;
        const int tx = tid & 31, ty = tid >> 5;
#pragma unroll
        for (int p = 0; p < 4; ++p)
            t[ty + p * 8][tx] = W[(size_t)(r0 + ty + p * 8) * SA_D + c0 + tx] * scale;
        __syncthreads();
#pragma unroll
        for (int p = 0; p < 4; ++p)
            Wt[(size_t)(c0 + ty + p * 8) * SA_D + r0 + tx] =
                __float2bfloat16(t[tx][ty + p * 8]);
    }
}

// ---------------- fused QKV GEMM, m97-class tile: BM=128 BN=64 BK=64 ----------------
__global__ __launch_bounds__(256) void gemm_qkv_kernel(
    const __hip_bfloat16* __restrict__ xbf, const __hip_bfloat16* __restrict__ WtAll,
    const float* __restrict__ bq, const float* __restrict__ bk, const float* __restrict__ bv,
    __hip_bfloat16* __restrict__ Qb, __hip_bfloat16* __restrict__ Kb,
    __hip_bfloat16* __restrict__ VtT)
{
    __shared__ __align__(16) char As[128 * 128];   // 128 rows x 64 bf16
    __shared__ __align__(16) char Bs[64 * 128];    // 64 cols  x 64 bf16

    const int tid = threadIdx.x;
    const int wave = tid >> 6, lane = tid & 63;
    const int m = lane & 15, quad = lane >> 4;
    const int wm = wave >> 1, wn = wave & 1;
    const int row0 = blockIdx.y * 128;
    const int col0 = blockIdx.x * 64;          // 0..3071 over concat(Q,K,V)
    const int w = col0 >> 10;                  // which weight (0=Q,1=K,2=V)
    const int cw0 = col0 & 1023;               // col within that weight
    const __hip_bfloat16* Bt = WtAll + (size_t)w * SA_D * SA_D;

    f32x4 acc[4][2];
#pragma unroll
    for (int mi = 0; mi < 4; ++mi)
#pragma unroll
        for (int ni = 0; ni < 2; ++ni) acc[mi][ni] = (f32x4){0.f, 0.f, 0.f, 0.f};

    const int sr = tid >> 3;   // 0..31
    const int sc = tid & 7;    // 16B chunk

    for (int k0 = 0; k0 < SA_D; k0 += 64) {
#pragma unroll
        for (int p = 0; p < 4; ++p) {
            const int r = p * 32 + sr;
            const int pc = (sc ^ (r & 7)) * 16;
            const char* ga = (const char*)(xbf + (size_t)(row0 + r) * SA_D + k0) + pc;
            __builtin_amdgcn_global_load_lds((gmem_t*)ga,
                (lds_t*)(As + p * 4096 + wave * 1024), 16, 0, 0);
        }
#pragma unroll
        for (int p = 0; p < 2; ++p) {
            const int r = p * 32 + sr;
            const int pc = (sc ^ (r & 7)) * 16;
            const char* gb = (const char*)(Bt + (size_t)(cw0 + r) * SA_D + k0) + pc;
            __builtin_amdgcn_global_load_lds((gmem_t*)gb,
                (lds_t*)(Bs + p * 4096 + wave * 1024), 16, 0, 0);
        }
        __syncthreads();

#pragma unroll
        for (int s = 0; s < 2; ++s) {
            bf16x8 af[4], bfr[2];
#pragma unroll
            for (int mi = 0; mi < 4; ++mi) {
                const int row = wm * 64 + mi * 16 + m;
                const int pc = (s * 4 + quad) ^ (row & 7);
                af[mi] = *reinterpret_cast<const bf16x8*>(As + row * 128 + pc * 16);
            }
#pragma unroll
            for (int ni = 0; ni < 2; ++ni) {
                const int col = wn * 32 + ni * 16 + m;
                const int pc = (s * 4 + quad) ^ (col & 7);
                bfr[ni] = *reinterpret_cast<const bf16x8*>(Bs + col * 128 + pc * 16);
            }
#pragma unroll
            for (int mi = 0; mi < 4; ++mi)
#pragma unroll
                for (int ni = 0; ni < 2; ++ni)
                    acc[mi][ni] = __builtin_amdgcn_mfma_f32_16x16x32_bf16(
                        af[mi], bfr[ni], acc[mi][ni], 0, 0, 0);
        }
        __syncthreads();
    }

    // epilogue: Q,K natural bf16; V transposed [dim][key] with per-64-block key
    // permutation jp = (j&15)*4 + (j>>4), j = mi*16 + quad*4 + reg.
    if (w < 2) {
        __hip_bfloat16* Out = w ? Kb : Qb;
        const float* bb = w ? bk : bq;
        const float bscale = w ? 1.0f : SC2;
#pragma unroll
        for (int ni = 0; ni < 2; ++ni) {
            const int cw = cw0 + wn * 32 + ni * 16 + m;
            const float bvv = bb[cw] * bscale;
#pragma unroll
            for (int mi = 0; mi < 4; ++mi) {
                const int rbase = row0 + wm * 64 + mi * 16 + quad * 4;
#pragma unroll
                for (int reg = 0; reg < 4; ++reg)
                    Out[(size_t)(rbase + reg) * SA_D + cw] =
                        __float2bfloat16(acc[mi][ni][reg] + bvv);
            }
        }
    } else {
#pragma unroll
        for (int ni = 0; ni < 2; ++ni) {
            const int cw = cw0 + wn * 32 + ni * 16 + m;
            const float bvv = bv[cw];
            const int kblk = row0 + wm * 64;   // 64-aligned key-block base
#pragma unroll
            for (int mi = 0; mi < 4; ++mi) {
#pragma unroll
                for (int reg = 0; reg < 4; ++reg) {
                    const int jp = (quad * 4 + reg) * 4 + mi;
                    VtT[(size_t)cw * SA_N + kblk + jp] =
                        __float2bfloat16(acc[mi][ni][reg] + bvv);
                }
            }
        }
    }
}

// ---------------- bf16 MFMA GEMM 64x64 (out-proj, exact R12) ----------------
__global__ __launch_bounds__(256) void gemm_out_kernel(
    const __hip_bfloat16* __restrict__ A, const __hip_bfloat16* __restrict__ Bt,
    const float* __restrict__ bias, float* __restrict__ Cout)
{
    __shared__ __align__(16) char As[64 * 128];
    __shared__ __align__(16) char Bs[64 * 128];
    const int tid = threadIdx.x;
    const int wave = tid >> 6, lane = tid & 63;
    const int m = lane & 15, quad = lane >> 4;
    const int wm = wave >> 1, wn = wave & 1;
    const int row0 = blockIdx.y * 64, col0 = blockIdx.x * 64;

    f32x4 acc[2][2];
#pragma unroll
    for (int i = 0; i < 2; ++i)
#pragma unroll
        for (int j = 0; j < 2; ++j) acc[i][j] = (f32x4){0.f, 0.f, 0.f, 0.f};

    const int sr = tid >> 3;
    const int sc = tid & 7;

    for (int k0 = 0; k0 < SA_D; k0 += 64) {
#pragma unroll
        for (int p = 0; p < 2; ++p) {
            const int r = p * 32 + sr;
            const int pc = (sc ^ (r & 7)) * 16;
            const char* ga = (const char*)(A + (size_t)(row0 + r) * SA_D + k0) + pc;
            __builtin_amdgcn_global_load_lds((gmem_t*)ga,
                (lds_t*)(As + p * 4096 + wave * 1024), 16, 0, 0);
            const char* gb = (const char*)(Bt + (size_t)(col0 + r) * SA_D + k0) + pc;
            __builtin_amdgcn_global_load_lds((gmem_t*)gb,
                (lds_t*)(Bs + p * 4096 + wave * 1024), 16, 0, 0);
        }
        __syncthreads();

#pragma unroll
        for (int s = 0; s < 2; ++s) {
            bf16x8 af[2], bfr[2];
#pragma unroll
            for (int mi = 0; mi < 2; ++mi) {
                const int row = wm * 32 + mi * 16 + m;
                const int pc = (s * 4 + quad) ^ (row & 7);
                af[mi] = *reinterpret_cast<const bf16x8*>(As + row * 128 + pc * 16);
            }
#pragma unroll
            for (int ni = 0; ni < 2; ++ni) {
                const int col = wn * 32 + ni * 16 + m;
                const int pc = (s * 4 + quad) ^ (col & 7);
                bfr[ni] = *reinterpret_cast<const bf16x8*>(Bs + col * 128 + pc * 16);
            }
#pragma unroll
            for (int mi = 0; mi < 2; ++mi)
#pragma unroll
                for (int ni = 0; ni < 2; ++ni)
                    acc[mi][ni] = __builtin_amdgcn_mfma_f32_16x16x32_bf16(
                        af[mi], bfr[ni], acc[mi][ni], 0, 0, 0);
        }
        __syncthreads();
    }

#pragma unroll
    for (int ni = 0; ni < 2; ++ni) {
        const int col = col0 + wn * 32 + ni * 16 + m;
        const float bv = bias[col];
#pragma unroll
        for (int mi = 0; mi < 2; ++mi) {
            const int rbase = row0 + wm * 32 + mi * 16 + quad * 4;
#pragma unroll
            for (int reg = 0; reg < 4; ++reg)
                Cout[(size_t)(rbase + reg) * SA_D + col] = acc[mi][ni][reg] + bv;
        }
    }
}

// ---------------- MFMA flash attention v11: staged K + register-direct V -------------
// Lesson from v10 (direct-global both operands, 70.9us, MfmaUtil 5%): operand
// latency must land where there is cover. K is consumed FIRST in the iteration
// -> stays LDS-staged with cross-iteration register prefetch. V is consumed
// LAST (after QK^T + exp2 + P pack, ~300-500cy of cover) -> read direct from
// global into registers (addressing verified correct by v10's pass), issued at
// the top of the compute phase. Removes 10 of 26 LDS ops/wave-iter.
// In-loop barriers are raw s_barrier with explicit lgkmcnt(0) on the ds_write
// side only (m201 recipe): __syncthreads' implicit vmcnt(0) drain is what kept
// v9's prefetch from surviving the barrier; now K-prefetch and V loads stay in
// flight across barriers.
__global__ __launch_bounds__(512, 4) void flash_mfma_kernel(
    const __hip_bfloat16* __restrict__ Qb,  // [N][D], pre-scaled by SC2
    const __hip_bfloat16* __restrict__ Kb,  // [N][D]
    const __hip_bfloat16* __restrict__ Vt,  // [D][N], keys permuted per 64-block
    __hip_bfloat16* __restrict__ O)         // [N][D]
{
    const int b = blockIdx.x;
    const int h = b & 15;
    const int qraw = b >> 4;
    const int qt = (qraw < 16) ? qraw : 47 - qraw;  // fold for CU balance
    const int row0 = qt * 64;
    const int ntiles = (qt >> 1) + 1;               // 128-key tiles

    const int tid = threadIdx.x;
    const int wave = tid >> 6, lane = tid & 63;
    const int g = wave >> 2, w4 = wave & 3;         // group, wave-in-group
    const int ln = lane & 15, quad = lane >> 4;

    __shared__ __align__(16) char Qs[64 * 128];     // [qrow][dim] bf16 (dead after hoist)
    __shared__ __align__(16) char Ks[128 * 128];    // [key][dim] bf16 (reused as merge buf)
    __shared__ __align__(16) char Ps[2][64 * 144];  // per-group [qrow][key'] bf16
    __shared__ float lmerge[64];

    // stage Q tile once (DMA; drained by the __syncthreads below)
    {
        const int r = wave * 8 + (lane >> 3);
        const int pc = ((lane & 7) ^ (r & 7)) * 16;
        const char* gq = (const char*)(Qb + (size_t)(row0 + r) * SA_D + h * SA_HD) + pc;
        __builtin_amdgcn_global_load_lds((gmem_t*)gq,
            (lds_t*)(Qs + wave * 1024), 16, 0, 0);
    }

    // K register prefetch (swizzled source addresses; LDS dest stays linear)
    const int kr0 = wave * 8 + (lane >> 3);           // K row within 64-row round
    const int kpc = ((lane & 7) ^ (kr0 & 7)) * 16;
    bf16x8 kreg[2];
    auto prefetchK = [&](int kt) {
#pragma unroll
        for (int p = 0; p < 2; ++p)
            kreg[p] = *reinterpret_cast<const bf16x8*>(
                (const char*)(Kb + (size_t)(kt * 128 + p * 64 + kr0) * SA_D + h * SA_HD) + kpc);
    };
    prefetchK(0);

    __syncthreads();   // Q DMA + kreg(0) drained

    // hoist loop-invariant Q fragments into registers
    bf16x8 afh[2];
    {
        const int mrow = w4 * 16 + ln;
#pragma unroll
        for (int s = 0; s < 2; ++s) {
            const int pca = (s * 4 + quad) ^ (mrow & 7);
            afh[s] = *reinterpret_cast<const bf16x8*>(Qs + mrow * 128 + pca * 16);
        }
    }

    f32x4 oacc[4], lacc;
#pragma unroll
    for (int dg = 0; dg < 4; ++dg) oacc[dg] = (f32x4){0.f, 0.f, 0.f, 0.f};
    lacc = (f32x4){0.f, 0.f, 0.f, 0.f};

    const short one_bf = (short)0x3F80;
    const bf16x8 ones = {one_bf, one_bf, one_bf, one_bf, one_bf, one_bf, one_bf, one_bf};

    // V direct-fragment base (bytes) — verified by v10's numerics pass:
    //   V frag (s2,dg): Vt + (h*64 + dg*16 + ln)*4096 + kt*256 + (g*8+s2*4+quad)*16
    const char* Vt8 = (const char*)Vt + (size_t)(h * 64 + ln) * 4096 + (g * 8 + quad) * 16;

    for (int kt = 0; kt < ntiles; ++kt) {
        __builtin_amdgcn_s_barrier();   // all waves done reading Ks (prev iter)
        // write prefetched K tile into LDS (linear dest, same layout as v6 DMA)
#pragma unroll
        for (int p = 0; p < 2; ++p)
            *reinterpret_cast<bf16x8*>(Ks + p * 8192 + wave * 1024 + lane * 16) = kreg[p];
        asm volatile("s_waitcnt lgkmcnt(0)" ::: "memory");  // K writes retired (NOT vmcnt)
        __builtin_amdgcn_s_barrier();   // K tile visible

        if (kt + 1 < ntiles) prefetchK(kt + 1);  // in flight through the whole compute phase

        // V fragments for THIS tile: global->reg, hidden under QK^T + exp2 + pack
        bf16x8 vfr[2][4];
        {
            const char* Vtk = Vt8 + (size_t)kt * 256;
#pragma unroll
            for (int s2 = 0; s2 < 2; ++s2)
#pragma unroll
                for (int dg = 0; dg < 4; ++dg)
                    vfr[s2][dg] = *reinterpret_cast<const bf16x8*>(
                        Vtk + (size_t)(dg * 16) * 4096 + s2 * 64);
        }

        // S = Q K^T : wave's 16 q-rows x group's 64 keys
        f32x4 sacc[4];
#pragma unroll
        for (int gg = 0; gg < 4; ++gg) sacc[gg] = (f32x4){0.f, 0.f, 0.f, 0.f};
        __builtin_amdgcn_s_setprio(1);
#pragma unroll
        for (int s = 0; s < 2; ++s) {
#pragma unroll
            for (int gg = 0; gg < 4; ++gg) {
                const int krow = g * 64 + gg * 16 + ln;
                const int pcb = (s * 4 + quad) ^ (krow & 7);
                bf16x8 bf = *reinterpret_cast<const bf16x8*>(Ks + krow * 128 + pcb * 16);
                sacc[gg] = __builtin_amdgcn_mfma_f32_16x16x32_bf16(afh[s], bf, sacc[gg], 0, 0, 0);
            }
        }
        __builtin_amdgcn_s_setprio(0);

        // P = exp2(S) + causal mask; packed b64 store per row (permuted keys)
        const bool last = (kt == ntiles - 1);
        const int prow_b = w4 * 16 + quad * 4;
        const int qrow_b = row0 + prow_b;
        char* Pg = Ps[g];
#pragma unroll
        for (int reg = 0; reg < 4; ++reg) {
            union { __hip_bfloat16 hh[4]; short4 s4; } u;
#pragma unroll
            for (int gg = 0; gg < 4; ++gg) {
                const int key = kt * 128 + g * 64 + gg * 16 + ln;
                float p = exp2f(sacc[gg][reg]);
                if (last && key > (qrow_b + reg)) p = 0.f;
                u.hh[gg] = __float2bfloat16(p);
            }
            *reinterpret_cast<short4*>(Pg + (prow_b + reg) * 144 + ln * 8) = u.s4;
        }

        // O += P V ; l += P . ones   (V from registers; k' order consistent)
        __builtin_amdgcn_s_setprio(1);
#pragma unroll
        for (int s2 = 0; s2 < 2; ++s2) {
            bf16x8 pf = *reinterpret_cast<const bf16x8*>(
                Pg + (w4 * 16 + ln) * 144 + s2 * 64 + quad * 16);
            lacc = __builtin_amdgcn_mfma_f32_16x16x32_bf16(pf, ones, lacc, 0, 0, 0);
#pragma unroll
            for (int dg = 0; dg < 4; ++dg)
                oacc[dg] = __builtin_amdgcn_mfma_f32_16x16x32_bf16(pf, vfr[s2][dg], oacc[dg], 0, 0, 0);
        }
        __builtin_amdgcn_s_setprio(0);
    }

    // merge groups: group 1 dumps fp32 partials into Ks (16 KB = 64x64 f32)
    __syncthreads();
    float* Kf = reinterpret_cast<float*>(Ks);
    if (g == 1) {
#pragma unroll
        for (int reg = 0; reg < 4; ++reg) {
            const int row = w4 * 16 + quad * 4 + reg;
#pragma unroll
            for (int dg = 0; dg < 4; ++dg)
                Kf[row * 64 + dg * 16 + ln] = oacc[dg][reg];
            if (ln == 0) lmerge[row] = lacc[reg];
        }
    }
    __syncthreads();
    if (g == 0) {
#pragma unroll
        for (int reg = 0; reg < 4; ++reg) {
            const int row = w4 * 16 + quad * 4 + reg;
            const float inv = 1.0f / (lacc[reg] + lmerge[row]);
            const int qrow = row0 + row;
#pragma unroll
            for (int dg = 0; dg < 4; ++dg)
                O[(size_t)qrow * SA_D + h * SA_HD + dg * 16 + ln] =
                    __float2bfloat16((oacc[dg][reg] + Kf[row * 64 + dg * 16 + ln]) * inv);
        }
    }
}

extern "C" void kernel_launch(void* const* d_in, const int* in_sizes, int n_in,
                              void* d_out, int out_size, void* d_ws, size_t ws_size,
                              hipStream_t stream) {
    const float* x  = (const float*)d_in[0];
    const float* Wq = (const float*)d_in[1];
    const float* bq = (const float*)d_in[2];
    const float* Wk = (const float*)d_in[3];
    const float* bk = (const float*)d_in[4];
    const float* Wv = (const float*)d_in[5];
    const float* bv = (const float*)d_in[6];
    const float* Wo = (const float*)d_in[7];
    const float* bo = (const float*)d_in[8];
    float* out = (float*)d_out;

    const size_t ND = (size_t)SA_N * SA_D;
    const size_t DD = (size_t)SA_D * SA_D;
    __hip_bfloat16* xbf   = (__hip_bfloat16*)d_ws;
    __hip_bfloat16* WtAll = xbf + ND;
    __hip_bfloat16* Qb    = WtAll + 4 * DD;
    __hip_bfloat16* Kb    = Qb + ND;
    __hip_bfloat16* VtT   = Kb + ND;
    __hip_bfloat16* Abf   = VtT + ND;

    prep_kernel<<<dim3(32, 32, 6), 256, 0, stream>>>(x, Wq, Wk, Wv, Wo, xbf, WtAll);
    gemm_qkv_kernel<<<dim3(3072 / 64, SA_N / 128), 256, 0, stream>>>(
        xbf, WtAll, bq, bk, bv, Qb, Kb, VtT);
    flash_mfma_kernel<<<dim3(512), 512, 0, stream>>>(Qb, Kb, VtT, Abf);
    gemm_out_kernel<<<dim3(SA_D / 64, SA_N / 64), 256, 0, stream>>>(
        Abf, WtAll + 3 * DD, bo, out);
}

// Round 7
// 138.005 us; speedup vs baseline: 1.3057x; 1.1404x over previous
//
#include <hip/hip_runtime.h>
#include <hip/hip_bf16.h>
#include <math.h>

#define SA_N 2048
#define SA_D 1024
#define SA_H 16
#define SA_HD 64

typedef __attribute__((ext_vector_type(8))) short bf16x8;
typedef __attribute__((ext_vector_type(4))) float f32x4;
typedef __attribute__((address_space(3))) void lds_t;
typedef __attribute__((address_space(1))) void gmem_t;

#define SC2 0.18033688011112042f   // (1/sqrt(64)) * log2(e), folded into Wq/bq

// ---------------- merged prep: x->bf16 and 4x W[K][N] -> bf16 Wt[N][K] ----------------
__global__ __launch_bounds__(256) void prep_kernel(
    const float* __restrict__ x,
    const float* __restrict__ Wq, const float* __restrict__ Wk,
    const float* __restrict__ Wv, const float* __restrict__ Wo,
    __hip_bfloat16* __restrict__ xbf, __hip_bfloat16* __restrict__ WtAll)
{
    const int tid = threadIdx.x;
    const int z = blockIdx.z;
    if (z < 2) {
        const int r = z * 1024 + blockIdx.y * 32 + (tid >> 3);
        const int c = blockIdx.x * 32 + (tid & 7) * 4;
        const size_t idx = (size_t)r * SA_D + c;
        float4 v = *reinterpret_cast<const float4*>(&x[idx]);
        union { __hip_bfloat16 hh[4]; short4 s4; } u;
        u.hh[0] = __float2bfloat16(v.x);
        u.hh[1] = __float2bfloat16(v.y);
        u.hh[2] = __float2bfloat16(v.z);
        u.hh[3] = __float2bfloat16(v.w);
        *reinterpret_cast<short4*>(&xbf[idx]) = u.s4;
    } else {
        const int w = z - 2;
        const float* W = (w == 0) ? Wq : (w == 1) ? Wk : (w == 2) ? Wv : Wo;
        const float scale = (w == 0) ? SC2 : 1.0f;
        __hip_bfloat16* Wt = WtAll + (size_t)w * SA_D * SA_D;
        __shared__ float t[32][33];
        const int c0 = blockIdx.x * 32, r0 = blockIdx.y * 32;
        const int tx = tid & 31, ty = tid >> 5;
#pragma unroll
        for (int p = 0; p < 4; ++p)
            t[ty + p * 8][tx] = W[(size_t)(r0 + ty + p * 8) * SA_D + c0 + tx] * scale;
        __syncthreads();
#pragma unroll
        for (int p = 0; p < 4; ++p)
            Wt[(size_t)(c0 + ty + p * 8) * SA_D + r0 + tx] =
                __float2bfloat16(t[tx][ty + p * 8]);
    }
}

// ---------------- fused QKV GEMM, m97-class tile: BM=128 BN=64 BK=64 ----------------
__global__ __launch_bounds__(256) void gemm_qkv_kernel(
    const __hip_bfloat16* __restrict__ xbf, const __hip_bfloat16* __restrict__ WtAll,
    const float* __restrict__ bq, const float* __restrict__ bk, const float* __restrict__ bv,
    __hip_bfloat16* __restrict__ Qb, __hip_bfloat16* __restrict__ Kb,
    __hip_bfloat16* __restrict__ VtT)
{
    __shared__ __align__(16) char As[128 * 128];   // 128 rows x 64 bf16
    __shared__ __align__(16) char Bs[64 * 128];    // 64 cols  x 64 bf16

    const int tid = threadIdx.x;
    const int wave = tid >> 6, lane = tid & 63;
    const int m = lane & 15, quad = lane >> 4;
    const int wm = wave >> 1, wn = wave & 1;
    const int row0 = blockIdx.y * 128;
    const int col0 = blockIdx.x * 64;          // 0..3071 over concat(Q,K,V)
    const int w = col0 >> 10;                  // which weight (0=Q,1=K,2=V)
    const int cw0 = col0 & 1023;               // col within that weight
    const __hip_bfloat16* Bt = WtAll + (size_t)w * SA_D * SA_D;

    f32x4 acc[4][2];
#pragma unroll
    for (int mi = 0; mi < 4; ++mi)
#pragma unroll
        for (int ni = 0; ni < 2; ++ni) acc[mi][ni] = (f32x4){0.f, 0.f, 0.f, 0.f};

    const int sr = tid >> 3;   // 0..31
    const int sc = tid & 7;    // 16B chunk

    for (int k0 = 0; k0 < SA_D; k0 += 64) {
#pragma unroll
        for (int p = 0; p < 4; ++p) {
            const int r = p * 32 + sr;
            const int pc = (sc ^ (r & 7)) * 16;
            const char* ga = (const char*)(xbf + (size_t)(row0 + r) * SA_D + k0) + pc;
            __builtin_amdgcn_global_load_lds((gmem_t*)ga,
                (lds_t*)(As + p * 4096 + wave * 1024), 16, 0, 0);
        }
#pragma unroll
        for (int p = 0; p < 2; ++p) {
            const int r = p * 32 + sr;
            const int pc = (sc ^ (r & 7)) * 16;
            const char* gb = (const char*)(Bt + (size_t)(cw0 + r) * SA_D + k0) + pc;
            __builtin_amdgcn_global_load_lds((gmem_t*)gb,
                (lds_t*)(Bs + p * 4096 + wave * 1024), 16, 0, 0);
        }
        __syncthreads();

#pragma unroll
        for (int s = 0; s < 2; ++s) {
            bf16x8 af[4], bfr[2];
#pragma unroll
            for (int mi = 0; mi < 4; ++mi) {
                const int row = wm * 64 + mi * 16 + m;
                const int pc = (s * 4 + quad) ^ (row & 7);
                af[mi] = *reinterpret_cast<const bf16x8*>(As + row * 128 + pc * 16);
            }
#pragma unroll
            for (int ni = 0; ni < 2; ++ni) {
                const int col = wn * 32 + ni * 16 + m;
                const int pc = (s * 4 + quad) ^ (col & 7);
                bfr[ni] = *reinterpret_cast<const bf16x8*>(Bs + col * 128 + pc * 16);
            }
#pragma unroll
            for (int mi = 0; mi < 4; ++mi)
#pragma unroll
                for (int ni = 0; ni < 2; ++ni)
                    acc[mi][ni] = __builtin_amdgcn_mfma_f32_16x16x32_bf16(
                        af[mi], bfr[ni], acc[mi][ni], 0, 0, 0);
        }
        __syncthreads();
    }

    // epilogue: Q,K natural bf16; V transposed [dim][key] with per-64-block key
    // permutation jp = (j&15)*4 + (j>>4), j = mi*16 + quad*4 + reg.
    if (w < 2) {
        __hip_bfloat16* Out = w ? Kb : Qb;
        const float* bb = w ? bk : bq;
        const float bscale = w ? 1.0f : SC2;
#pragma unroll
        for (int ni = 0; ni < 2; ++ni) {
            const int cw = cw0 + wn * 32 + ni * 16 + m;
            const float bvv = bb[cw] * bscale;
#pragma unroll
            for (int mi = 0; mi < 4; ++mi) {
                const int rbase = row0 + wm * 64 + mi * 16 + quad * 4;
#pragma unroll
                for (int reg = 0; reg < 4; ++reg)
                    Out[(size_t)(rbase + reg) * SA_D + cw] =
                        __float2bfloat16(acc[mi][ni][reg] + bvv);
            }
        }
    } else {
#pragma unroll
        for (int ni = 0; ni < 2; ++ni) {
            const int cw = cw0 + wn * 32 + ni * 16 + m;
            const float bvv = bv[cw];
            const int kblk = row0 + wm * 64;   // 64-aligned key-block base
#pragma unroll
            for (int mi = 0; mi < 4; ++mi) {
#pragma unroll
                for (int reg = 0; reg < 4; ++reg) {
                    const int jp = (quad * 4 + reg) * 4 + mi;
                    VtT[(size_t)cw * SA_N + kblk + jp] =
                        __float2bfloat16(acc[mi][ni][reg] + bvv);
                }
            }
        }
    }
}

// ---------------- bf16 MFMA GEMM 64x64 (out-proj, exact R12) ----------------
__global__ __launch_bounds__(256) void gemm_out_kernel(
    const __hip_bfloat16* __restrict__ A, const __hip_bfloat16* __restrict__ Bt,
    const float* __restrict__ bias, float* __restrict__ Cout)
{
    __shared__ __align__(16) char As[64 * 128];
    __shared__ __align__(16) char Bs[64 * 128];
    const int tid = threadIdx.x;
    const int wave = tid >> 6, lane = tid & 63;
    const int m = lane & 15, quad = lane >> 4;
    const int wm = wave >> 1, wn = wave & 1;
    const int row0 = blockIdx.y * 64, col0 = blockIdx.x * 64;

    f32x4 acc[2][2];
#pragma unroll
    for (int i = 0; i < 2; ++i)
#pragma unroll
        for (int j = 0; j < 2; ++j) acc[i][j] = (f32x4){0.f, 0.f, 0.f, 0.f};

    const int sr = tid >> 3;
    const int sc = tid & 7;

    for (int k0 = 0; k0 < SA_D; k0 += 64) {
#pragma unroll
        for (int p = 0; p < 2; ++p) {
            const int r = p * 32 + sr;
            const int pc = (sc ^ (r & 7)) * 16;
            const char* ga = (const char*)(A + (size_t)(row0 + r) * SA_D + k0) + pc;
            __builtin_amdgcn_global_load_lds((gmem_t*)ga,
                (lds_t*)(As + p * 4096 + wave * 1024), 16, 0, 0);
            const char* gb = (const char*)(Bt + (size_t)(col0 + r) * SA_D + k0) + pc;
            __builtin_amdgcn_global_load_lds((gmem_t*)gb,
                (lds_t*)(Bs + p * 4096 + wave * 1024), 16, 0, 0);
        }
        __syncthreads();

#pragma unroll
        for (int s = 0; s < 2; ++s) {
            bf16x8 af[2], bfr[2];
#pragma unroll
            for (int mi = 0; mi < 2; ++mi) {
                const int row = wm * 32 + mi * 16 + m;
                const int pc = (s * 4 + quad) ^ (row & 7);
                af[mi] = *reinterpret_cast<const bf16x8*>(As + row * 128 + pc * 16);
            }
#pragma unroll
            for (int ni = 0; ni < 2; ++ni) {
                const int col = wn * 32 + ni * 16 + m;
                const int pc = (s * 4 + quad) ^ (col & 7);
                bfr[ni] = *reinterpret_cast<const bf16x8*>(Bs + col * 128 + pc * 16);
            }
#pragma unroll
            for (int mi = 0; mi < 2; ++mi)
#pragma unroll
                for (int ni = 0; ni < 2; ++ni)
                    acc[mi][ni] = __builtin_amdgcn_mfma_f32_16x16x32_bf16(
                        af[mi], bfr[ni], acc[mi][ni], 0, 0, 0);
        }
        __syncthreads();
    }

#pragma unroll
    for (int ni = 0; ni < 2; ++ni) {
        const int col = col0 + wn * 32 + ni * 16 + m;
        const float bv = bias[col];
#pragma unroll
        for (int mi = 0; mi < 2; ++mi) {
            const int rbase = row0 + wm * 32 + mi * 16 + quad * 4;
#pragma unroll
            for (int reg = 0; reg < 4; ++reg)
                Cout[(size_t)(rbase + reg) * SA_D + col] = acc[mi][ni][reg] + bv;
        }
    }
}

// ---------------- MFMA flash attention v12: v9 compute + non-draining barriers -------
// ISOLATED test of the barrier-drain theory (v11 confounded it with the V-gather
// regression). K AND V stay register-prefetched + LDS-staged exactly as v9.
// Only change vs v9: the two in-loop __syncthreads (which drain vmcnt(0),
// forcing each iteration to synchronously eat the next tile's global-load
// latency) become raw s_barrier pairs with an explicit lgkmcnt(0) after the
// ds_writes. The kt+1 prefetch is issued right after the visibility barrier
// and stays in flight through the whole compute phase; the compiler's exact
// vmcnt wait lands at the next iteration's ds_writes.
__global__ __launch_bounds__(512, 4) void flash_mfma_kernel(
    const __hip_bfloat16* __restrict__ Qb,  // [N][D], pre-scaled by SC2
    const __hip_bfloat16* __restrict__ Kb,  // [N][D]
    const __hip_bfloat16* __restrict__ Vt,  // [D][N], keys permuted per 64-block
    __hip_bfloat16* __restrict__ O)         // [N][D]
{
    const int b = blockIdx.x;
    const int h = b & 15;
    const int qraw = b >> 4;
    const int qt = (qraw < 16) ? qraw : 47 - qraw;  // fold for CU balance
    const int row0 = qt * 64;
    const int ntiles = (qt >> 1) + 1;               // 128-key tiles

    const int tid = threadIdx.x;
    const int wave = tid >> 6, lane = tid & 63;
    const int g = wave >> 2, w4 = wave & 3;         // group, wave-in-group
    const int ln = lane & 15, quad = lane >> 4;

    __shared__ __align__(16) char Qs[64 * 128];     // [qrow][dim] bf16 (dead after hoist)
    __shared__ __align__(16) char Ks[128 * 128];    // [key][dim] bf16 (reused as merge buf)
    __shared__ __align__(16) char Vs[64 * 256];     // [dim][key'] bf16, 128 keys/row
    __shared__ __align__(16) char Ps[2][64 * 144];  // per-group [qrow][key'] bf16
    __shared__ float lmerge[64];

    // stage Q tile once (DMA; drained by the __syncthreads below)
    {
        const int r = wave * 8 + (lane >> 3);
        const int pc = ((lane & 7) ^ (r & 7)) * 16;
        const char* gq = (const char*)(Qb + (size_t)(row0 + r) * SA_D + h * SA_HD) + pc;
        __builtin_amdgcn_global_load_lds((gmem_t*)gq,
            (lds_t*)(Qs + wave * 1024), 16, 0, 0);
    }

    // K/V register prefetch (same swizzled addresses the v6 DMA used)
    const int kr0 = wave * 8 + (lane >> 3);           // K row within 64-row round
    const int kpc = ((lane & 7) ^ (kr0 & 7)) * 16;
    const int vr0 = wave * 4 + (lane >> 4);           // V row within 32-row round
    const int vpc = ((lane & 15) ^ (vr0 & 15)) * 16;
    bf16x8 kreg[2], vreg[2];

    auto prefetch = [&](int kt) {
#pragma unroll
        for (int p = 0; p < 2; ++p) {
            kreg[p] = *reinterpret_cast<const bf16x8*>(
                (const char*)(Kb + (size_t)(kt * 128 + p * 64 + kr0) * SA_D + h * SA_HD) + kpc);
            vreg[p] = *reinterpret_cast<const bf16x8*>(
                (const char*)(Vt + (size_t)(h * SA_HD + p * 32 + vr0) * SA_N + kt * 128) + vpc);
        }
    };
    prefetch(0);

    __syncthreads();   // Q DMA drained (full drain OK here, once)

    // hoist loop-invariant Q fragments into registers
    bf16x8 afh[2];
    {
        const int mrow = w4 * 16 + ln;
#pragma unroll
        for (int s = 0; s < 2; ++s) {
            const int pca = (s * 4 + quad) ^ (mrow & 7);
            afh[s] = *reinterpret_cast<const bf16x8*>(Qs + mrow * 128 + pca * 16);
        }
    }

    f32x4 oacc[4], lacc;
#pragma unroll
    for (int dg = 0; dg < 4; ++dg) oacc[dg] = (f32x4){0.f, 0.f, 0.f, 0.f};
    lacc = (f32x4){0.f, 0.f, 0.f, 0.f};

    const short one_bf = (short)0x3F80;
    const bf16x8 ones = {one_bf, one_bf, one_bf, one_bf, one_bf, one_bf, one_bf, one_bf};

    for (int kt = 0; kt < ntiles; ++kt) {
        __builtin_amdgcn_s_barrier();   // all waves done reading Ks/Vs (prev iter); no drain
        // write prefetched tile into LDS (identical physical layout to v6 DMA).
        // Compiler inserts the exact vmcnt wait for kreg/vreg here — the loads
        // had the entire previous compute phase to land.
#pragma unroll
        for (int p = 0; p < 2; ++p) {
            *reinterpret_cast<bf16x8*>(Ks + p * 8192 + wave * 1024 + lane * 16) = kreg[p];
            *reinterpret_cast<bf16x8*>(Vs + p * 8192 + wave * 1024 + lane * 16) = vreg[p];
        }
        asm volatile("s_waitcnt lgkmcnt(0)" ::: "memory");  // LDS writes retired (NOT vmcnt)
        __builtin_amdgcn_s_barrier();   // K/V tile visible

        if (kt + 1 < ntiles) prefetch(kt + 1);  // in flight through the whole compute phase

        // S = Q K^T : wave's 16 q-rows x group's 64 keys
        f32x4 sacc[4];
#pragma unroll
        for (int gg = 0; gg < 4; ++gg) sacc[gg] = (f32x4){0.f, 0.f, 0.f, 0.f};
        __builtin_amdgcn_s_setprio(1);
#pragma unroll
        for (int s = 0; s < 2; ++s) {
#pragma unroll
            for (int gg = 0; gg < 4; ++gg) {
                const int krow = g * 64 + gg * 16 + ln;
                const int pcb = (s * 4 + quad) ^ (krow & 7);
                bf16x8 bf = *reinterpret_cast<const bf16x8*>(Ks + krow * 128 + pcb * 16);
                sacc[gg] = __builtin_amdgcn_mfma_f32_16x16x32_bf16(afh[s], bf, sacc[gg], 0, 0, 0);
            }
        }
        __builtin_amdgcn_s_setprio(0);

        // P = exp2(S) + causal mask; packed b64 store per row (permuted keys)
        const bool last = (kt == ntiles - 1);
        const int prow_b = w4 * 16 + quad * 4;
        const int qrow_b = row0 + prow_b;
        char* Pg = Ps[g];
#pragma unroll
        for (int reg = 0; reg < 4; ++reg) {
            union { __hip_bfloat16 hh[4]; short4 s4; } u;
#pragma unroll
            for (int gg = 0; gg < 4; ++gg) {
                const int key = kt * 128 + g * 64 + gg * 16 + ln;
                float p = exp2f(sacc[gg][reg]);
                if (last && key > (qrow_b + reg)) p = 0.f;
                u.hh[gg] = __float2bfloat16(p);
            }
            *reinterpret_cast<short4*>(Pg + (prow_b + reg) * 144 + ln * 8) = u.s4;
        }

        // O += P V ; l += P . ones   (k' order consistent between P and Vs)
        __builtin_amdgcn_s_setprio(1);
#pragma unroll
        for (int s2 = 0; s2 < 2; ++s2) {
            bf16x8 pf = *reinterpret_cast<const bf16x8*>(
                Pg + (w4 * 16 + ln) * 144 + s2 * 64 + quad * 16);
            lacc = __builtin_amdgcn_mfma_f32_16x16x32_bf16(pf, ones, lacc, 0, 0, 0);
#pragma unroll
            for (int dg = 0; dg < 4; ++dg) {
                const int vrow = dg * 16 + ln;
                const int kc = g * 8 + s2 * 4 + quad;
                const int pcb = (kc ^ (vrow & 15)) * 16;
                bf16x8 vf = *reinterpret_cast<const bf16x8*>(Vs + vrow * 256 + pcb);
                oacc[dg] = __builtin_amdgcn_mfma_f32_16x16x32_bf16(pf, vf, oacc[dg], 0, 0, 0);
            }
        }
        __builtin_amdgcn_s_setprio(0);
    }

    // merge groups: group 1 dumps fp32 partials into Ks (16 KB = 64x64 f32)
    __syncthreads();
    float* Kf = reinterpret_cast<float*>(Ks);
    if (g == 1) {
#pragma unroll
        for (int reg = 0; reg < 4; ++reg) {
            const int row = w4 * 16 + quad * 4 + reg;
#pragma unroll
            for (int dg = 0; dg < 4; ++dg)
                Kf[row * 64 + dg * 16 + ln] = oacc[dg][reg];
            if (ln == 0) lmerge[row] = lacc[reg];
        }
    }
    __syncthreads();
    if (g == 0) {
#pragma unroll
        for (int reg = 0; reg < 4; ++reg) {
            const int row = w4 * 16 + quad * 4 + reg;
            const float inv = 1.0f / (lacc[reg] + lmerge[row]);
            const int qrow = row0 + row;
#pragma unroll
            for (int dg = 0; dg < 4; ++dg)
                O[(size_t)qrow * SA_D + h * SA_HD + dg * 16 + ln] =
                    __float2bfloat16((oacc[dg][reg] + Kf[row * 64 + dg * 16 + ln]) * inv);
        }
    }
}

extern "C" void kernel_launch(void* const* d_in, const int* in_sizes, int n_in,
                              void* d_out, int out_size, void* d_ws, size_t ws_size,
                              hipStream_t stream) {
    const float* x  = (const float*)d_in[0];
    const float* Wq = (const float*)d_in[1];
    const float* bq = (const float*)d_in[2];
    const float* Wk = (const float*)d_in[3];
    const float* bk = (const float*)d_in[4];
    const float* Wv = (const float*)d_in[5];
    const float* bv = (const float*)d_in[6];
    const float* Wo = (const float*)d_in[7];
    const float* bo = (const float*)d_in[8];
    float* out = (float*)d_out;

    const size_t ND = (size_t)SA_N * SA_D;
    const size_t DD = (size_t)SA_D * SA_D;
    __hip_bfloat16* xbf   = (__hip_bfloat16*)d_ws;
    __hip_bfloat16* WtAll = xbf + ND;
    __hip_bfloat16* Qb    = WtAll + 4 * DD;
    __hip_bfloat16* Kb    = Qb + ND;
    __hip_bfloat16* VtT   = Kb + ND;
    __hip_bfloat16* Abf   = VtT + ND;

    prep_kernel<<<dim3(32, 32, 6), 256, 0, stream>>>(x, Wq, Wk, Wv, Wo, xbf, WtAll);
    gemm_qkv_kernel<<<dim3(3072 / 64, SA_N / 128), 256, 0, stream>>>(
        xbf, WtAll, bq, bk, bv, Qb, Kb, VtT);
    flash_mfma_kernel<<<dim3(512), 512, 0, stream>>>(Qb, Kb, VtT, Abf);
    gemm_out_kernel<<<dim3(SA_D / 64, SA_N / 64), 256, 0, stream>>>(
        Abf, WtAll + 3 * DD, bo, out);
}

// Round 8
// 135.730 us; speedup vs baseline: 1.3276x; 1.0168x over previous
//
#include <hip/hip_runtime.h>
#include <hip/hip_bf16.h>
#include <math.h>

#define SA_N 2048
#define SA_D 1024
#define SA_H 16
#define SA_HD 64

typedef __attribute__((ext_vector_type(8))) short bf16x8;
typedef __attribute__((ext_vector_type(4))) float f32x4;
typedef __attribute__((address_space(3))) void lds_t;
typedef __attribute__((address_space(1))) void gmem_t;

#define SC2 0.18033688011112042f   // (1/sqrt(64)) * log2(e), folded into Wq/bq

// ---------------- merged prep: x->bf16 and 4x W[K][N] -> bf16 Wt[N][K] ----------------
__global__ __launch_bounds__(256) void prep_kernel(
    const float* __restrict__ x,
    const float* __restrict__ Wq, const float* __restrict__ Wk,
    const float* __restrict__ Wv, const float* __restrict__ Wo,
    __hip_bfloat16* __restrict__ xbf, __hip_bfloat16* __restrict__ WtAll)
{
    const int tid = threadIdx.x;
    const int z = blockIdx.z;
    if (z < 2) {
        const int r = z * 1024 + blockIdx.y * 32 + (tid >> 3);
        const int c = blockIdx.x * 32 + (tid & 7) * 4;
        const size_t idx = (size_t)r * SA_D + c;
        float4 v = *reinterpret_cast<const float4*>(&x[idx]);
        union { __hip_bfloat16 hh[4]; short4 s4; } u;
        u.hh[0] = __float2bfloat16(v.x);
        u.hh[1] = __float2bfloat16(v.y);
        u.hh[2] = __float2bfloat16(v.z);
        u.hh[3] = __float2bfloat16(v.w);
        *reinterpret_cast<short4*>(&xbf[idx]) = u.s4;
    } else {
        const int w = z - 2;
        const float* W = (w == 0) ? Wq : (w == 1) ? Wk : (w == 2) ? Wv : Wo;
        const float scale = (w == 0) ? SC2 : 1.0f;
        __hip_bfloat16* Wt = WtAll + (size_t)w * SA_D * SA_D;
        __shared__ float t[32][33];
        const int c0 = blockIdx.x * 32, r0 = blockIdx.y * 32;
        const int tx = tid & 31, ty = tid >> 5;
#pragma unroll
        for (int p = 0; p < 4; ++p)
            t[ty + p * 8][tx] = W[(size_t)(r0 + ty + p * 8) * SA_D + c0 + tx] * scale;
        __syncthreads();
#pragma unroll
        for (int p = 0; p < 4; ++p)
            Wt[(size_t)(c0 + ty + p * 8) * SA_D + r0 + tx] =
                __float2bfloat16(t[tx][ty + p * 8]);
    }
}

// ---------------- fused QKV GEMM: BM=128 BN=64 BK=128 (barrier-amortized) ----------
// BK 64->128: halves the per-K-step vmcnt(0) barrier drains (the m97 ~20% stall;
// drain cost = latency of the LAST load, independent of load count) and doubles
// MFMA per barrier-pair (32 vs 16). LDS 24->48 KB keeps 3 blocks/CU (144<=160KB,
// pinned via __launch_bounds__(256,3)). Rows are now 256B = 16 chunks; XOR-16
// swizzle (ch ^ (r&15)) gives <=2-way bank aliasing on fragment reads (free).
__global__ __launch_bounds__(256, 3) void gemm_qkv_kernel(
    const __hip_bfloat16* __restrict__ xbf, const __hip_bfloat16* __restrict__ WtAll,
    const float* __restrict__ bq, const float* __restrict__ bk, const float* __restrict__ bv,
    __hip_bfloat16* __restrict__ Qb, __hip_bfloat16* __restrict__ Kb,
    __hip_bfloat16* __restrict__ VtT)
{
    __shared__ __align__(16) char As[128 * 256];   // 128 rows x 128 bf16
    __shared__ __align__(16) char Bs[64 * 256];    // 64 cols  x 128 bf16

    const int tid = threadIdx.x;
    const int wave = tid >> 6, lane = tid & 63;
    const int m = lane & 15, quad = lane >> 4;
    const int wm = wave >> 1, wn = wave & 1;
    const int row0 = blockIdx.y * 128;
    const int col0 = blockIdx.x * 64;          // 0..3071 over concat(Q,K,V)
    const int w = col0 >> 10;                  // which weight (0=Q,1=K,2=V)
    const int cw0 = col0 & 1023;               // col within that weight
    const __hip_bfloat16* Bt = WtAll + (size_t)w * SA_D * SA_D;

    f32x4 acc[4][2];
#pragma unroll
    for (int mi = 0; mi < 4; ++mi)
#pragma unroll
        for (int ni = 0; ni < 2; ++ni) acc[mi][ni] = (f32x4){0.f, 0.f, 0.f, 0.f};

    const int sr = tid >> 4;   // 0..15 (row within 16-row round)
    const int sc = tid & 15;   // 16B chunk 0..15

    for (int k0 = 0; k0 < SA_D; k0 += 128) {
#pragma unroll
        for (int p = 0; p < 8; ++p) {
            const int r = p * 16 + sr;
            const int pc = (sc ^ (r & 15)) * 16;
            const char* ga = (const char*)(xbf + (size_t)(row0 + r) * SA_D + k0) + pc;
            __builtin_amdgcn_global_load_lds((gmem_t*)ga,
                (lds_t*)(As + p * 4096 + wave * 1024), 16, 0, 0);
        }
#pragma unroll
        for (int p = 0; p < 4; ++p) {
            const int r = p * 16 + sr;
            const int pc = (sc ^ (r & 15)) * 16;
            const char* gb = (const char*)(Bt + (size_t)(cw0 + r) * SA_D + k0) + pc;
            __builtin_amdgcn_global_load_lds((gmem_t*)gb,
                (lds_t*)(Bs + p * 4096 + wave * 1024), 16, 0, 0);
        }
        __syncthreads();

#pragma unroll
        for (int s = 0; s < 4; ++s) {
            bf16x8 af[4], bfr[2];
#pragma unroll
            for (int mi = 0; mi < 4; ++mi) {
                const int row = wm * 64 + mi * 16 + m;
                const int pc = (s * 4 + quad) ^ (row & 15);
                af[mi] = *reinterpret_cast<const bf16x8*>(As + row * 256 + pc * 16);
            }
#pragma unroll
            for (int ni = 0; ni < 2; ++ni) {
                const int col = wn * 32 + ni * 16 + m;
                const int pc = (s * 4 + quad) ^ (col & 15);
                bfr[ni] = *reinterpret_cast<const bf16x8*>(Bs + col * 256 + pc * 16);
            }
#pragma unroll
            for (int mi = 0; mi < 4; ++mi)
#pragma unroll
                for (int ni = 0; ni < 2; ++ni)
                    acc[mi][ni] = __builtin_amdgcn_mfma_f32_16x16x32_bf16(
                        af[mi], bfr[ni], acc[mi][ni], 0, 0, 0);
        }
        __syncthreads();
    }

    // epilogue: Q,K natural bf16; V transposed [dim][key] with per-64-block key
    // permutation jp = (j&15)*4 + (j>>4), j = mi*16 + quad*4 + reg.
    if (w < 2) {
        __hip_bfloat16* Out = w ? Kb : Qb;
        const float* bb = w ? bk : bq;
        const float bscale = w ? 1.0f : SC2;
#pragma unroll
        for (int ni = 0; ni < 2; ++ni) {
            const int cw = cw0 + wn * 32 + ni * 16 + m;
            const float bvv = bb[cw] * bscale;
#pragma unroll
            for (int mi = 0; mi < 4; ++mi) {
                const int rbase = row0 + wm * 64 + mi * 16 + quad * 4;
#pragma unroll
                for (int reg = 0; reg < 4; ++reg)
                    Out[(size_t)(rbase + reg) * SA_D + cw] =
                        __float2bfloat16(acc[mi][ni][reg] + bvv);
            }
        }
    } else {
#pragma unroll
        for (int ni = 0; ni < 2; ++ni) {
            const int cw = cw0 + wn * 32 + ni * 16 + m;
            const float bvv = bv[cw];
            const int kblk = row0 + wm * 64;   // 64-aligned key-block base
#pragma unroll
            for (int mi = 0; mi < 4; ++mi) {
#pragma unroll
                for (int reg = 0; reg < 4; ++reg) {
                    const int jp = (quad * 4 + reg) * 4 + mi;
                    VtT[(size_t)cw * SA_N + kblk + jp] =
                        __float2bfloat16(acc[mi][ni][reg] + bvv);
                }
            }
        }
    }
}

// ---------------- bf16 MFMA GEMM 64x64, BK=128 (out-proj) ----------------
__global__ __launch_bounds__(256) void gemm_out_kernel(
    const __hip_bfloat16* __restrict__ A, const __hip_bfloat16* __restrict__ Bt,
    const float* __restrict__ bias, float* __restrict__ Cout)
{
    __shared__ __align__(16) char As[64 * 256];
    __shared__ __align__(16) char Bs[64 * 256];
    const int tid = threadIdx.x;
    const int wave = tid >> 6, lane = tid & 63;
    const int m = lane & 15, quad = lane >> 4;
    const int wm = wave >> 1, wn = wave & 1;
    const int row0 = blockIdx.y * 64, col0 = blockIdx.x * 64;

    f32x4 acc[2][2];
#pragma unroll
    for (int i = 0; i < 2; ++i)
#pragma unroll
        for (int j = 0; j < 2; ++j) acc[i][j] = (f32x4){0.f, 0.f, 0.f, 0.f};

    const int sr = tid >> 4;   // 0..15
    const int sc = tid & 15;   // chunk

    for (int k0 = 0; k0 < SA_D; k0 += 128) {
#pragma unroll
        for (int p = 0; p < 4; ++p) {
            const int r = p * 16 + sr;
            const int pc = (sc ^ (r & 15)) * 16;
            const char* ga = (const char*)(A + (size_t)(row0 + r) * SA_D + k0) + pc;
            __builtin_amdgcn_global_load_lds((gmem_t*)ga,
                (lds_t*)(As + p * 4096 + wave * 1024), 16, 0, 0);
            const char* gb = (const char*)(Bt + (size_t)(col0 + r) * SA_D + k0) + pc;
            __builtin_amdgcn_global_load_lds((gmem_t*)gb,
                (lds_t*)(Bs + p * 4096 + wave * 1024), 16, 0, 0);
        }
        __syncthreads();

#pragma unroll
        for (int s = 0; s < 4; ++s) {
            bf16x8 af[2], bfr[2];
#pragma unroll
            for (int mi = 0; mi < 2; ++mi) {
                const int row = wm * 32 + mi * 16 + m;
                const int pc = (s * 4 + quad) ^ (row & 15);
                af[mi] = *reinterpret_cast<const bf16x8*>(As + row * 256 + pc * 16);
            }
#pragma unroll
            for (int ni = 0; ni < 2; ++ni) {
                const int col = wn * 32 + ni * 16 + m;
                const int pc = (s * 4 + quad) ^ (col & 15);
                bfr[ni] = *reinterpret_cast<const bf16x8*>(Bs + col * 256 + pc * 16);
            }
#pragma unroll
            for (int mi = 0; mi < 2; ++mi)
#pragma unroll
                for (int ni = 0; ni < 2; ++ni)
                    acc[mi][ni] = __builtin_amdgcn_mfma_f32_16x16x32_bf16(
                        af[mi], bfr[ni], acc[mi][ni], 0, 0, 0);
        }
        __syncthreads();
    }

#pragma unroll
    for (int ni = 0; ni < 2; ++ni) {
        const int col = col0 + wn * 32 + ni * 16 + m;
        const float bv = bias[col];
#pragma unroll
        for (int mi = 0; mi < 2; ++mi) {
            const int rbase = row0 + wm * 32 + mi * 16 + quad * 4;
#pragma unroll
            for (int reg = 0; reg < 4; ++reg)
                Cout[(size_t)(rbase + reg) * SA_D + col] = acc[mi][ni][reg] + bv;
        }
    }
}

// ---------------- MFMA flash attention v9 (measured best: 137.1us total) ------------
// Q-hoist + setprio + prefetch-before-barrier; staged K AND V (v10/v11 proved
// direct-global operands are latency-poison); plain __syncthreads (v12 proved
// the barrier vmcnt drain is NOT the dominant cost — raw barriers were neutral).
__global__ __launch_bounds__(512, 4) void flash_mfma_kernel(
    const __hip_bfloat16* __restrict__ Qb,  // [N][D], pre-scaled by SC2
    const __hip_bfloat16* __restrict__ Kb,  // [N][D]
    const __hip_bfloat16* __restrict__ Vt,  // [D][N], keys permuted per 64-block
    __hip_bfloat16* __restrict__ O)         // [N][D]
{
    const int b = blockIdx.x;
    const int h = b & 15;
    const int qraw = b >> 4;
    const int qt = (qraw < 16) ? qraw : 47 - qraw;  // fold for CU balance
    const int row0 = qt * 64;
    const int ntiles = (qt >> 1) + 1;               // 128-key tiles

    const int tid = threadIdx.x;
    const int wave = tid >> 6, lane = tid & 63;
    const int g = wave >> 2, w4 = wave & 3;         // group, wave-in-group
    const int ln = lane & 15, quad = lane >> 4;

    __shared__ __align__(16) char Qs[64 * 128];     // [qrow][dim] bf16 (dead after hoist)
    __shared__ __align__(16) char Ks[128 * 128];    // [key][dim] bf16 (reused as merge buf)
    __shared__ __align__(16) char Vs[64 * 256];     // [dim][key'] bf16, 128 keys/row
    __shared__ __align__(16) char Ps[2][64 * 144];  // per-group [qrow][key'] bf16
    __shared__ float lmerge[64];

    // stage Q tile once (DMA)
    {
        const int r = wave * 8 + (lane >> 3);
        const int pc = ((lane & 7) ^ (r & 7)) * 16;
        const char* gq = (const char*)(Qb + (size_t)(row0 + r) * SA_D + h * SA_HD) + pc;
        __builtin_amdgcn_global_load_lds((gmem_t*)gq,
            (lds_t*)(Qs + wave * 1024), 16, 0, 0);
    }

    // K/V register prefetch (same swizzled addresses the v6 DMA used)
    const int kr0 = wave * 8 + (lane >> 3);           // K row within 64-row round
    const int kpc = ((lane & 7) ^ (kr0 & 7)) * 16;
    const int vr0 = wave * 4 + (lane >> 4);           // V row within 32-row round
    const int vpc = ((lane & 15) ^ (vr0 & 15)) * 16;
    bf16x8 kreg[2], vreg[2];

    auto prefetch = [&](int kt) {
#pragma unroll
        for (int p = 0; p < 2; ++p) {
            kreg[p] = *reinterpret_cast<const bf16x8*>(
                (const char*)(Kb + (size_t)(kt * 128 + p * 64 + kr0) * SA_D + h * SA_HD) + kpc);
            vreg[p] = *reinterpret_cast<const bf16x8*>(
                (const char*)(Vt + (size_t)(h * SA_HD + p * 32 + vr0) * SA_N + kt * 128) + vpc);
        }
    };
    prefetch(0);

    // drain Q DMA, then hoist the loop-invariant Q fragments into registers
    __syncthreads();
    bf16x8 afh[2];
    {
        const int mrow = w4 * 16 + ln;
#pragma unroll
        for (int s = 0; s < 2; ++s) {
            const int pca = (s * 4 + quad) ^ (mrow & 7);
            afh[s] = *reinterpret_cast<const bf16x8*>(Qs + mrow * 128 + pca * 16);
        }
    }

    f32x4 oacc[4], lacc;
#pragma unroll
    for (int dg = 0; dg < 4; ++dg) oacc[dg] = (f32x4){0.f, 0.f, 0.f, 0.f};
    lacc = (f32x4){0.f, 0.f, 0.f, 0.f};

    const short one_bf = (short)0x3F80;
    const bf16x8 ones = {one_bf, one_bf, one_bf, one_bf, one_bf, one_bf, one_bf, one_bf};

    for (int kt = 0; kt < ntiles; ++kt) {
        __syncthreads();   // all waves done reading Ks/Vs (prev iter)
        // write prefetched tile into LDS (identical physical layout to v6 DMA)
#pragma unroll
        for (int p = 0; p < 2; ++p) {
            *reinterpret_cast<bf16x8*>(Ks + p * 8192 + wave * 1024 + lane * 16) = kreg[p];
            *reinterpret_cast<bf16x8*>(Vs + p * 8192 + wave * 1024 + lane * 16) = vreg[p];
        }
        if (kt + 1 < ntiles) prefetch(kt + 1);   // in flight across the barrier
        __syncthreads();   // writes visible

        // S = Q K^T : wave's 16 q-rows x group's 64 keys
        f32x4 sacc[4];
#pragma unroll
        for (int gg = 0; gg < 4; ++gg) sacc[gg] = (f32x4){0.f, 0.f, 0.f, 0.f};
        __builtin_amdgcn_s_setprio(1);
#pragma unroll
        for (int s = 0; s < 2; ++s) {
#pragma unroll
            for (int gg = 0; gg < 4; ++gg) {
                const int krow = g * 64 + gg * 16 + ln;
                const int pcb = (s * 4 + quad) ^ (krow & 7);
                bf16x8 bf = *reinterpret_cast<const bf16x8*>(Ks + krow * 128 + pcb * 16);
                sacc[gg] = __builtin_amdgcn_mfma_f32_16x16x32_bf16(afh[s], bf, sacc[gg], 0, 0, 0);
            }
        }
        __builtin_amdgcn_s_setprio(0);

        // P = exp2(S) + causal mask; packed b64 store per row (permuted keys)
        const bool last = (kt == ntiles - 1);
        const int prow_b = w4 * 16 + quad * 4;
        const int qrow_b = row0 + prow_b;
        char* Pg = Ps[g];
#pragma unroll
        for (int reg = 0; reg < 4; ++reg) {
            union { __hip_bfloat16 hh[4]; short4 s4; } u;
#pragma unroll
            for (int gg = 0; gg < 4; ++gg) {
                const int key = kt * 128 + g * 64 + gg * 16 + ln;
                float p = exp2f(sacc[gg][reg]);
                if (last && key > (qrow_b + reg)) p = 0.f;
                u.hh[gg] = __float2bfloat16(p);
            }
            *reinterpret_cast<short4*>(Pg + (prow_b + reg) * 144 + ln * 8) = u.s4;
        }

        // O += P V ; l += P . ones   (k' order consistent between P and Vs)
        __builtin_amdgcn_s_setprio(1);
#pragma unroll
        for (int s2 = 0; s2 < 2; ++s2) {
            bf16x8 pf = *reinterpret_cast<const bf16x8*>(
                Pg + (w4 * 16 + ln) * 144 + s2 * 64 + quad * 16);
            lacc = __builtin_amdgcn_mfma_f32_16x16x32_bf16(pf, ones, lacc, 0, 0, 0);
#pragma unroll
            for (int dg = 0; dg < 4; ++dg) {
                const int vrow = dg * 16 + ln;
                const int kc = g * 8 + s2 * 4 + quad;
                const int pcb = (kc ^ (vrow & 15)) * 16;
                bf16x8 vf = *reinterpret_cast<const bf16x8*>(Vs + vrow * 256 + pcb);
                oacc[dg] = __builtin_amdgcn_mfma_f32_16x16x32_bf16(pf, vf, oacc[dg], 0, 0, 0);
            }
        }
        __builtin_amdgcn_s_setprio(0);
    }

    // merge groups: group 1 dumps fp32 partials into Ks (16 KB = 64x64 f32)
    __syncthreads();
    float* Kf = reinterpret_cast<float*>(Ks);
    if (g == 1) {
#pragma unroll
        for (int reg = 0; reg < 4; ++reg) {
            const int row = w4 * 16 + quad * 4 + reg;
#pragma unroll
            for (int dg = 0; dg < 4; ++dg)
                Kf[row * 64 + dg * 16 + ln] = oacc[dg][reg];
            if (ln == 0) lmerge[row] = lacc[reg];
        }
    }
    __syncthreads();
    if (g == 0) {
#pragma unroll
        for (int reg = 0; reg < 4; ++reg) {
            const int row = w4 * 16 + quad * 4 + reg;
            const float inv = 1.0f / (lacc[reg] + lmerge[row]);
            const int qrow = row0 + row;
#pragma unroll
            for (int dg = 0; dg < 4; ++dg)
                O[(size_t)qrow * SA_D + h * SA_HD + dg * 16 + ln] =
                    __float2bfloat16((oacc[dg][reg] + Kf[row * 64 + dg * 16 + ln]) * inv);
        }
    }
}

extern "C" void kernel_launch(void* const* d_in, const int* in_sizes, int n_in,
                              void* d_out, int out_size, void* d_ws, size_t ws_size,
                              hipStream_t stream) {
    const float* x  = (const float*)d_in[0];
    const float* Wq = (const float*)d_in[1];
    const float* bq = (const float*)d_in[2];
    const float* Wk = (const float*)d_in[3];
    const float* bk = (const float*)d_in[4];
    const float* Wv = (const float*)d_in[5];
    const float* bv = (const float*)d_in[6];
    const float* Wo = (const float*)d_in[7];
    const float* bo = (const float*)d_in[8];
    float* out = (float*)d_out;

    const size_t ND = (size_t)SA_N * SA_D;
    const size_t DD = (size_t)SA_D * SA_D;
    __hip_bfloat16* xbf   = (__hip_bfloat16*)d_ws;
    __hip_bfloat16* WtAll = xbf + ND;
    __hip_bfloat16* Qb    = WtAll + 4 * DD;
    __hip_bfloat16* Kb    = Qb + ND;
    __hip_bfloat16* VtT   = Kb + ND;
    __hip_bfloat16* Abf   = VtT + ND;

    prep_kernel<<<dim3(32, 32, 6), 256, 0, stream>>>(x, Wq, Wk, Wv, Wo, xbf, WtAll);
    gemm_qkv_kernel<<<dim3(3072 / 64, SA_N / 128), 256, 0, stream>>>(
        xbf, WtAll, bq, bk, bv, Qb, Kb, VtT);
    flash_mfma_kernel<<<dim3(512), 512, 0, stream>>>(Qb, Kb, VtT, Abf);
    gemm_out_kernel<<<dim3(SA_D / 64, SA_N / 64), 256, 0, stream>>>(
        Abf, WtAll + 3 * DD, bo, out);
}

// Round 9
// 132.949 us; speedup vs baseline: 1.3553x; 1.0209x over previous
//
#include <hip/hip_runtime.h>
#include <hip/hip_bf16.h>
#include <math.h>

#define SA_N 2048
#define SA_D 1024
#define SA_H 16
#define SA_HD 64

typedef __attribute__((ext_vector_type(8))) short bf16x8;
typedef __attribute__((ext_vector_type(4))) float f32x4;
typedef __attribute__((address_space(3))) void lds_t;
typedef __attribute__((address_space(1))) void gmem_t;

#define SC2 0.18033688011112042f   // (1/sqrt(64)) * log2(e), folded into Wq/bq

// ---------------- merged prep: x->bf16 and 4x W[K][N] -> bf16 Wt[N][K] ----------------
__global__ __launch_bounds__(256) void prep_kernel(
    const float* __restrict__ x,
    const float* __restrict__ Wq, const float* __restrict__ Wk,
    const float* __restrict__ Wv, const float* __restrict__ Wo,
    __hip_bfloat16* __restrict__ xbf, __hip_bfloat16* __restrict__ WtAll)
{
    const int tid = threadIdx.x;
    const int z = blockIdx.z;
    if (z < 2) {
        const int r = z * 1024 + blockIdx.y * 32 + (tid >> 3);
        const int c = blockIdx.x * 32 + (tid & 7) * 4;
        const size_t idx = (size_t)r * SA_D + c;
        float4 v = *reinterpret_cast<const float4*>(&x[idx]);
        union { __hip_bfloat16 hh[4]; short4 s4; } u;
        u.hh[0] = __float2bfloat16(v.x);
        u.hh[1] = __float2bfloat16(v.y);
        u.hh[2] = __float2bfloat16(v.z);
        u.hh[3] = __float2bfloat16(v.w);
        *reinterpret_cast<short4*>(&xbf[idx]) = u.s4;
    } else {
        const int w = z - 2;
        const float* W = (w == 0) ? Wq : (w == 1) ? Wk : (w == 2) ? Wv : Wo;
        const float scale = (w == 0) ? SC2 : 1.0f;
        __hip_bfloat16* Wt = WtAll + (size_t)w * SA_D * SA_D;
        __shared__ float t[32][33];
        const int c0 = blockIdx.x * 32, r0 = blockIdx.y * 32;
        const int tx = tid & 31, ty = tid >> 5;
#pragma unroll
        for (int p = 0; p < 4; ++p)
            t[ty + p * 8][tx] = W[(size_t)(r0 + ty + p * 8) * SA_D + c0 + tx] * scale;
        __syncthreads();
#pragma unroll
        for (int p = 0; p < 4; ++p)
            Wt[(size_t)(c0 + ty + p * 8) * SA_D + r0 + tx] =
                __float2bfloat16(t[tx][ty + p * 8]);
    }
}

// ---------------- fused QKV GEMM: BM=128 BN=64 BK=128 (barrier-amortized) ----------
__global__ __launch_bounds__(256, 3) void gemm_qkv_kernel(
    const __hip_bfloat16* __restrict__ xbf, const __hip_bfloat16* __restrict__ WtAll,
    const float* __restrict__ bq, const float* __restrict__ bk, const float* __restrict__ bv,
    __hip_bfloat16* __restrict__ Qb, __hip_bfloat16* __restrict__ Kb,
    __hip_bfloat16* __restrict__ VtT)
{
    __shared__ __align__(16) char As[128 * 256];   // 128 rows x 128 bf16
    __shared__ __align__(16) char Bs[64 * 256];    // 64 cols  x 128 bf16

    const int tid = threadIdx.x;
    const int wave = tid >> 6, lane = tid & 63;
    const int m = lane & 15, quad = lane >> 4;
    const int wm = wave >> 1, wn = wave & 1;
    const int row0 = blockIdx.y * 128;
    const int col0 = blockIdx.x * 64;          // 0..3071 over concat(Q,K,V)
    const int w = col0 >> 10;                  // which weight (0=Q,1=K,2=V)
    const int cw0 = col0 & 1023;               // col within that weight
    const __hip_bfloat16* Bt = WtAll + (size_t)w * SA_D * SA_D;

    f32x4 acc[4][2];
#pragma unroll
    for (int mi = 0; mi < 4; ++mi)
#pragma unroll
        for (int ni = 0; ni < 2; ++ni) acc[mi][ni] = (f32x4){0.f, 0.f, 0.f, 0.f};

    const int sr = tid >> 4;   // 0..15 (row within 16-row round)
    const int sc = tid & 15;   // 16B chunk 0..15

    for (int k0 = 0; k0 < SA_D; k0 += 128) {
#pragma unroll
        for (int p = 0; p < 8; ++p) {
            const int r = p * 16 + sr;
            const int pc = (sc ^ (r & 15)) * 16;
            const char* ga = (const char*)(xbf + (size_t)(row0 + r) * SA_D + k0) + pc;
            __builtin_amdgcn_global_load_lds((gmem_t*)ga,
                (lds_t*)(As + p * 4096 + wave * 1024), 16, 0, 0);
        }
#pragma unroll
        for (int p = 0; p < 4; ++p) {
            const int r = p * 16 + sr;
            const int pc = (sc ^ (r & 15)) * 16;
            const char* gb = (const char*)(Bt + (size_t)(cw0 + r) * SA_D + k0) + pc;
            __builtin_amdgcn_global_load_lds((gmem_t*)gb,
                (lds_t*)(Bs + p * 4096 + wave * 1024), 16, 0, 0);
        }
        __syncthreads();

#pragma unroll
        for (int s = 0; s < 4; ++s) {
            bf16x8 af[4], bfr[2];
#pragma unroll
            for (int mi = 0; mi < 4; ++mi) {
                const int row = wm * 64 + mi * 16 + m;
                const int pc = (s * 4 + quad) ^ (row & 15);
                af[mi] = *reinterpret_cast<const bf16x8*>(As + row * 256 + pc * 16);
            }
#pragma unroll
            for (int ni = 0; ni < 2; ++ni) {
                const int col = wn * 32 + ni * 16 + m;
                const int pc = (s * 4 + quad) ^ (col & 15);
                bfr[ni] = *reinterpret_cast<const bf16x8*>(Bs + col * 256 + pc * 16);
            }
#pragma unroll
            for (int mi = 0; mi < 4; ++mi)
#pragma unroll
                for (int ni = 0; ni < 2; ++ni)
                    acc[mi][ni] = __builtin_amdgcn_mfma_f32_16x16x32_bf16(
                        af[mi], bfr[ni], acc[mi][ni], 0, 0, 0);
        }
        __syncthreads();
    }

    // epilogue: Q,K natural bf16; V transposed [dim][key] with per-64-block key
    // permutation jp = (j&15)*4 + (j>>4), j = mi*16 + quad*4 + reg.
    if (w < 2) {
        __hip_bfloat16* Out = w ? Kb : Qb;
        const float* bb = w ? bk : bq;
        const float bscale = w ? 1.0f : SC2;
#pragma unroll
        for (int ni = 0; ni < 2; ++ni) {
            const int cw = cw0 + wn * 32 + ni * 16 + m;
            const float bvv = bb[cw] * bscale;
#pragma unroll
            for (int mi = 0; mi < 4; ++mi) {
                const int rbase = row0 + wm * 64 + mi * 16 + quad * 4;
#pragma unroll
                for (int reg = 0; reg < 4; ++reg)
                    Out[(size_t)(rbase + reg) * SA_D + cw] =
                        __float2bfloat16(acc[mi][ni][reg] + bvv);
            }
        }
    } else {
#pragma unroll
        for (int ni = 0; ni < 2; ++ni) {
            const int cw = cw0 + wn * 32 + ni * 16 + m;
            const float bvv = bv[cw];
            const int kblk = row0 + wm * 64;   // 64-aligned key-block base
#pragma unroll
            for (int mi = 0; mi < 4; ++mi) {
#pragma unroll
                for (int reg = 0; reg < 4; ++reg) {
                    const int jp = (quad * 4 + reg) * 4 + mi;
                    VtT[(size_t)cw * SA_N + kblk + jp] =
                        __float2bfloat16(acc[mi][ni][reg] + bvv);
                }
            }
        }
    }
}

// ---------------- bf16 MFMA GEMM 64x64, BK=128 (out-proj) ----------------
__global__ __launch_bounds__(256) void gemm_out_kernel(
    const __hip_bfloat16* __restrict__ A, const __hip_bfloat16* __restrict__ Bt,
    const float* __restrict__ bias, float* __restrict__ Cout)
{
    __shared__ __align__(16) char As[64 * 256];
    __shared__ __align__(16) char Bs[64 * 256];
    const int tid = threadIdx.x;
    const int wave = tid >> 6, lane = tid & 63;
    const int m = lane & 15, quad = lane >> 4;
    const int wm = wave >> 1, wn = wave & 1;
    const int row0 = blockIdx.y * 64, col0 = blockIdx.x * 64;

    f32x4 acc[2][2];
#pragma unroll
    for (int i = 0; i < 2; ++i)
#pragma unroll
        for (int j = 0; j < 2; ++j) acc[i][j] = (f32x4){0.f, 0.f, 0.f, 0.f};

    const int sr = tid >> 4;   // 0..15
    const int sc = tid & 15;   // chunk

    for (int k0 = 0; k0 < SA_D; k0 += 128) {
#pragma unroll
        for (int p = 0; p < 4; ++p) {
            const int r = p * 16 + sr;
            const int pc = (sc ^ (r & 15)) * 16;
            const char* ga = (const char*)(A + (size_t)(row0 + r) * SA_D + k0) + pc;
            __builtin_amdgcn_global_load_lds((gmem_t*)ga,
                (lds_t*)(As + p * 4096 + wave * 1024), 16, 0, 0);
            const char* gb = (const char*)(Bt + (size_t)(col0 + r) * SA_D + k0) + pc;
            __builtin_amdgcn_global_load_lds((gmem_t*)gb,
                (lds_t*)(Bs + p * 4096 + wave * 1024), 16, 0, 0);
        }
        __syncthreads();

#pragma unroll
        for (int s = 0; s < 4; ++s) {
            bf16x8 af[2], bfr[2];
#pragma unroll
            for (int mi = 0; mi < 2; ++mi) {
                const int row = wm * 32 + mi * 16 + m;
                const int pc = (s * 4 + quad) ^ (row & 15);
                af[mi] = *reinterpret_cast<const bf16x8*>(As + row * 256 + pc * 16);
            }
#pragma unroll
            for (int ni = 0; ni < 2; ++ni) {
                const int col = wn * 32 + ni * 16 + m;
                const int pc = (s * 4 + quad) ^ (col & 15);
                bfr[ni] = *reinterpret_cast<const bf16x8*>(Bs + col * 256 + pc * 16);
            }
#pragma unroll
            for (int mi = 0; mi < 2; ++mi)
#pragma unroll
                for (int ni = 0; ni < 2; ++ni)
                    acc[mi][ni] = __builtin_amdgcn_mfma_f32_16x16x32_bf16(
                        af[mi], bfr[ni], acc[mi][ni], 0, 0, 0);
        }
        __syncthreads();
    }

#pragma unroll
    for (int ni = 0; ni < 2; ++ni) {
        const int col = col0 + wn * 32 + ni * 16 + m;
        const float bv = bias[col];
#pragma unroll
        for (int mi = 0; mi < 2; ++mi) {
            const int rbase = row0 + wm * 32 + mi * 16 + quad * 4;
#pragma unroll
            for (int reg = 0; reg < 4; ++reg)
                Cout[(size_t)(rbase + reg) * SA_D + col] = acc[mi][ni][reg] + bv;
        }
    }
}

// ---------------- MFMA flash attention v13: v9 + Q-direct-global (occupancy) --------
// v9 structure (measured best) with ONE change: Q fragments are loaded directly
// from global into registers (same per-lane fragment addressing the v10 K-direct
// path verified numerically; 2x 16B loads/lane, ONCE per block). This kills the
// Qs staging buffer entirely: LDS 58.6 -> 50.3 KB, occupancy 2 -> 3 blocks/CU
// (16 -> 24 waves/CU, +50% TLP) for this latency-bound kernel. Everything else
// (staged K/V, prefetch placement, setprio, P round-trip, merge) is unchanged.
__global__ __launch_bounds__(512, 4) void flash_mfma_kernel(
    const __hip_bfloat16* __restrict__ Qb,  // [N][D], pre-scaled by SC2
    const __hip_bfloat16* __restrict__ Kb,  // [N][D]
    const __hip_bfloat16* __restrict__ Vt,  // [D][N], keys permuted per 64-block
    __hip_bfloat16* __restrict__ O)         // [N][D]
{
    const int b = blockIdx.x;
    const int h = b & 15;
    const int qraw = b >> 4;
    const int qt = (qraw < 16) ? qraw : 47 - qraw;  // fold for CU balance
    const int row0 = qt * 64;
    const int ntiles = (qt >> 1) + 1;               // 128-key tiles

    const int tid = threadIdx.x;
    const int wave = tid >> 6, lane = tid & 63;
    const int g = wave >> 2, w4 = wave & 3;         // group, wave-in-group
    const int ln = lane & 15, quad = lane >> 4;

    __shared__ __align__(16) char Ks[128 * 128];    // [key][dim] bf16 (reused as merge buf)
    __shared__ __align__(16) char Vs[64 * 256];     // [dim][key'] bf16, 128 keys/row
    __shared__ __align__(16) char Ps[2][64 * 144];  // per-group [qrow][key'] bf16
    __shared__ float lmerge[64];

    // Q fragments direct from global (once per block; no LDS staging).
    // frag s: Qb + (row0 + w4*16+ln)*2048B + h*128B + (s*4+quad)*16B
    bf16x8 afh[2];
    {
        const char* gq = (const char*)Qb + (size_t)(row0 + w4 * 16 + ln) * (SA_D * 2)
                         + h * (SA_HD * 2) + quad * 16;
#pragma unroll
        for (int s = 0; s < 2; ++s)
            afh[s] = *reinterpret_cast<const bf16x8*>(gq + s * 64);
    }

    // K/V register prefetch (same swizzled addresses the v6 DMA used)
    const int kr0 = wave * 8 + (lane >> 3);           // K row within 64-row round
    const int kpc = ((lane & 7) ^ (kr0 & 7)) * 16;
    const int vr0 = wave * 4 + (lane >> 4);           // V row within 32-row round
    const int vpc = ((lane & 15) ^ (vr0 & 15)) * 16;
    bf16x8 kreg[2], vreg[2];

    auto prefetch = [&](int kt) {
#pragma unroll
        for (int p = 0; p < 2; ++p) {
            kreg[p] = *reinterpret_cast<const bf16x8*>(
                (const char*)(Kb + (size_t)(kt * 128 + p * 64 + kr0) * SA_D + h * SA_HD) + kpc);
            vreg[p] = *reinterpret_cast<const bf16x8*>(
                (const char*)(Vt + (size_t)(h * SA_HD + p * 32 + vr0) * SA_N + kt * 128) + vpc);
        }
    };
    prefetch(0);

    f32x4 oacc[4], lacc;
#pragma unroll
    for (int dg = 0; dg < 4; ++dg) oacc[dg] = (f32x4){0.f, 0.f, 0.f, 0.f};
    lacc = (f32x4){0.f, 0.f, 0.f, 0.f};

    const short one_bf = (short)0x3F80;
    const bf16x8 ones = {one_bf, one_bf, one_bf, one_bf, one_bf, one_bf, one_bf, one_bf};

    for (int kt = 0; kt < ntiles; ++kt) {
        __syncthreads();   // all waves done reading Ks/Vs (prev iter)
        // write prefetched tile into LDS (identical physical layout to v6 DMA)
#pragma unroll
        for (int p = 0; p < 2; ++p) {
            *reinterpret_cast<bf16x8*>(Ks + p * 8192 + wave * 1024 + lane * 16) = kreg[p];
            *reinterpret_cast<bf16x8*>(Vs + p * 8192 + wave * 1024 + lane * 16) = vreg[p];
        }
        if (kt + 1 < ntiles) prefetch(kt + 1);   // in flight across the barrier
        __syncthreads();   // writes visible

        // S = Q K^T : wave's 16 q-rows x group's 64 keys
        f32x4 sacc[4];
#pragma unroll
        for (int gg = 0; gg < 4; ++gg) sacc[gg] = (f32x4){0.f, 0.f, 0.f, 0.f};
        __builtin_amdgcn_s_setprio(1);
#pragma unroll
        for (int s = 0; s < 2; ++s) {
#pragma unroll
            for (int gg = 0; gg < 4; ++gg) {
                const int krow = g * 64 + gg * 16 + ln;
                const int pcb = (s * 4 + quad) ^ (krow & 7);
                bf16x8 bf = *reinterpret_cast<const bf16x8*>(Ks + krow * 128 + pcb * 16);
                sacc[gg] = __builtin_amdgcn_mfma_f32_16x16x32_bf16(afh[s], bf, sacc[gg], 0, 0, 0);
            }
        }
        __builtin_amdgcn_s_setprio(0);

        // P = exp2(S) + causal mask; packed b64 store per row (permuted keys)
        const bool last = (kt == ntiles - 1);
        const int prow_b = w4 * 16 + quad * 4;
        const int qrow_b = row0 + prow_b;
        char* Pg = Ps[g];
#pragma unroll
        for (int reg = 0; reg < 4; ++reg) {
            union { __hip_bfloat16 hh[4]; short4 s4; } u;
#pragma unroll
            for (int gg = 0; gg < 4; ++gg) {
                const int key = kt * 128 + g * 64 + gg * 16 + ln;
                float p = exp2f(sacc[gg][reg]);
                if (last && key > (qrow_b + reg)) p = 0.f;
                u.hh[gg] = __float2bfloat16(p);
            }
            *reinterpret_cast<short4*>(Pg + (prow_b + reg) * 144 + ln * 8) = u.s4;
        }

        // O += P V ; l += P . ones   (k' order consistent between P and Vs)
        __builtin_amdgcn_s_setprio(1);
#pragma unroll
        for (int s2 = 0; s2 < 2; ++s2) {
            bf16x8 pf = *reinterpret_cast<const bf16x8*>(
                Pg + (w4 * 16 + ln) * 144 + s2 * 64 + quad * 16);
            lacc = __builtin_amdgcn_mfma_f32_16x16x32_bf16(pf, ones, lacc, 0, 0, 0);
#pragma unroll
            for (int dg = 0; dg < 4; ++dg) {
                const int vrow = dg * 16 + ln;
                const int kc = g * 8 + s2 * 4 + quad;
                const int pcb = (kc ^ (vrow & 15)) * 16;
                bf16x8 vf = *reinterpret_cast<const bf16x8*>(Vs + vrow * 256 + pcb);
                oacc[dg] = __builtin_amdgcn_mfma_f32_16x16x32_bf16(pf, vf, oacc[dg], 0, 0, 0);
            }
        }
        __builtin_amdgcn_s_setprio(0);
    }

    // merge groups: group 1 dumps fp32 partials into Ks (16 KB = 64x64 f32)
    __syncthreads();
    float* Kf = reinterpret_cast<float*>(Ks);
    if (g == 1) {
#pragma unroll
        for (int reg = 0; reg < 4; ++reg) {
            const int row = w4 * 16 + quad * 4 + reg;
#pragma unroll
            for (int dg = 0; dg < 4; ++dg)
                Kf[row * 64 + dg * 16 + ln] = oacc[dg][reg];
            if (ln == 0) lmerge[row] = lacc[reg];
        }
    }
    __syncthreads();
    if (g == 0) {
#pragma unroll
        for (int reg = 0; reg < 4; ++reg) {
            const int row = w4 * 16 + quad * 4 + reg;
            const float inv = 1.0f / (lacc[reg] + lmerge[row]);
            const int qrow = row0 + row;
#pragma unroll
            for (int dg = 0; dg < 4; ++dg)
                O[(size_t)qrow * SA_D + h * SA_HD + dg * 16 + ln] =
                    __float2bfloat16((oacc[dg][reg] + Kf[row * 64 + dg * 16 + ln]) * inv);
        }
    }
}

extern "C" void kernel_launch(void* const* d_in, const int* in_sizes, int n_in,
                              void* d_out, int out_size, void* d_ws, size_t ws_size,
                              hipStream_t stream) {
    const float* x  = (const float*)d_in[0];
    const float* Wq = (const float*)d_in[1];
    const float* bq = (const float*)d_in[2];
    const float* Wk = (const float*)d_in[3];
    const float* bk = (const float*)d_in[4];
    const float* Wv = (const float*)d_in[5];
    const float* bv = (const float*)d_in[6];
    const float* Wo = (const float*)d_in[7];
    const float* bo = (const float*)d_in[8];
    float* out = (float*)d_out;

    const size_t ND = (size_t)SA_N * SA_D;
    const size_t DD = (size_t)SA_D * SA_D;
    __hip_bfloat16* xbf   = (__hip_bfloat16*)d_ws;
    __hip_bfloat16* WtAll = xbf + ND;
    __hip_bfloat16* Qb    = WtAll + 4 * DD;
    __hip_bfloat16* Kb    = Qb + ND;
    __hip_bfloat16* VtT   = Kb + ND;
    __hip_bfloat16* Abf   = VtT + ND;

    prep_kernel<<<dim3(32, 32, 6), 256, 0, stream>>>(x, Wq, Wk, Wv, Wo, xbf, WtAll);
    gemm_qkv_kernel<<<dim3(3072 / 64, SA_N / 128), 256, 0, stream>>>(
        xbf, WtAll, bq, bk, bv, Qb, Kb, VtT);
    flash_mfma_kernel<<<dim3(512), 512, 0, stream>>>(Qb, Kb, VtT, Abf);
    gemm_out_kernel<<<dim3(SA_D / 64, SA_N / 64), 256, 0, stream>>>(
        Abf, WtAll + 3 * DD, bo, out);
}